// Round 3
// baseline (319.708 us; speedup 1.0000x reference)
//
#include <hip/hip_runtime.h>
#include <hip/hip_bf16.h>

#define S_LEN  2048
#define DMODEL 2048
#define NH     32
#define NG     8
#define DK     64
#define DV     64

typedef short bf16x8 __attribute__((ext_vector_type(8)));
typedef float f32x4  __attribute__((ext_vector_type(4)));

__device__ __forceinline__ ushort f32_to_bf16(float f) {
    uint u = __float_as_uint(f);
    return (ushort)((u + 0x7fffu + ((u >> 16) & 1u)) >> 16);   // RNE
}
__device__ __forceinline__ float bf16_to_f32(ushort h) {
    return __uint_as_float(((uint)h) << 16);
}
__device__ __forceinline__ uint pack_bf16x2(float a, float b) {
    return (uint)f32_to_bf16(a) | ((uint)f32_to_bf16(b) << 16);
}

// ------------------------------------------- fused cast f32->bf16 (q,k,v in one)
__global__ void cast3_f32_to_bf16(const float* __restrict__ q,
                                  const float* __restrict__ k,
                                  const float* __restrict__ v,
                                  ushort* __restrict__ xq,
                                  ushort* __restrict__ xk,
                                  ushort* __restrict__ xv, int n8) {
    const float* in  = blockIdx.z == 0 ? q  : (blockIdx.z == 1 ? k  : v);
    ushort*      out = blockIdx.z == 0 ? xq : (blockIdx.z == 1 ? xk : xv);
    int i = blockIdx.x * blockDim.x + threadIdx.x;
    const int stride = gridDim.x * blockDim.x;
    for (; i < n8; i += stride) {
        const float4 a = ((const float4*)in)[2 * i];
        const float4 b = ((const float4*)in)[2 * i + 1];
        uint4 o;
        o.x = (uint)f32_to_bf16(a.x) | ((uint)f32_to_bf16(a.y) << 16);
        o.y = (uint)f32_to_bf16(a.z) | ((uint)f32_to_bf16(a.w) << 16);
        o.z = (uint)f32_to_bf16(b.x) | ((uint)f32_to_bf16(b.y) << 16);
        o.w = (uint)f32_to_bf16(b.z) | ((uint)f32_to_bf16(b.w) << 16);
        ((uint4*)out)[i] = o;
    }
}

// ---------------------- fused W[K][N] f32 -> Wt[N][K] bf16 for all four weights
// grid.x block ranges: [0,64) Wq, [64,80) Wk, [80,96) Wv, [96,160) Wo. K=2048.
__global__ void transpose_cast4(const float* __restrict__ Wq,
                                const float* __restrict__ Wk,
                                const float* __restrict__ Wv,
                                const float* __restrict__ Wo,
                                ushort* __restrict__ Wqt, ushort* __restrict__ Wkt,
                                ushort* __restrict__ Wvt, ushort* __restrict__ Wot) {
    __shared__ float t[32][33];
    int bx = blockIdx.x;
    const float* W; ushort* Wt; int N;
    if (bx < 64)      { W = Wq; Wt = Wqt; N = 2048; }
    else if (bx < 80) { W = Wk; Wt = Wkt; N = 512;  bx -= 64; }
    else if (bx < 96) { W = Wv; Wt = Wvt; N = 512;  bx -= 80; }
    else              { W = Wo; Wt = Wot; N = 2048; bx -= 96; }
    const int n0 = bx * 32, k0 = blockIdx.y * 32;
    const int tx = threadIdx.x, ty = threadIdx.y;   // 32 x 8
#pragma unroll
    for (int i = 0; i < 4; ++i)
        t[ty + 8 * i][tx] = W[(size_t)(k0 + ty + 8 * i) * N + n0 + tx];
    __syncthreads();
#pragma unroll
    for (int i = 0; i < 4; ++i)
        Wt[(size_t)(n0 + ty + 8 * i) * 2048 + k0 + tx] = f32_to_bf16(t[tx][ty + 8 * i]);
}

// ------------------------------------------------------------- bf16 MFMA GEMM
// C[M][N] = (A[M][K] @ Bt[N][K]^T + bias) * scale.  128(M)x64(N) tile, 4 waves
// stacked in M (each: 32 rows x 64 cols = 2x4 frags of mfma_f32_16x16x32_bf16).
// LDS row stride 40 shorts (2-way bank alias only). Register-prefetch
// pipeline: next k-tile's global loads issue before compute.
// MODE: 0 = bf16 C, 1 = f32 C, 2 = bf16 C^T (V^T, output stride S_LEN) via LDS.
template <int MODE>
__device__ __forceinline__ void gemm_body_128x64(
        const ushort* __restrict__ A, const ushort* __restrict__ Bt,
        const float* __restrict__ bias, void* __restrict__ Cv,
        ushort* As, ushort* Bs, ushort* Ts, int N, int K, float scale) {
    const int tid  = threadIdx.x;
    const int lane = tid & 63, wave = tid >> 6;
    const int l15 = lane & 15, quad = lane >> 4;
    const int row0 = blockIdx.y * 128, col0 = blockIdx.x * 64;

    f32x4 acc[2][4];
#pragma unroll
    for (int i = 0; i < 2; ++i)
#pragma unroll
        for (int j = 0; j < 4; ++j) { f32x4 z = {0.f,0.f,0.f,0.f}; acc[i][j] = z; }

    // staging coords: A 128x32 (2 b128/thread), B 64x32 (1 b128/thread)
    const int ar = tid >> 1, ak = (tid & 1) * 16;
    const int br = tid >> 2, bk = (tid & 3) * 8;
    const ushort* aptr = A  + (size_t)(row0 + ar) * K + ak;
    const ushort* bptr = Bt + (size_t)(col0 + br) * K + bk;

    bf16x8 a0 = *(const bf16x8*)(aptr);
    bf16x8 a1 = *(const bf16x8*)(aptr + 8);
    bf16x8 b0 = *(const bf16x8*)(bptr);

    for (int k0 = 0; k0 < K; k0 += 32) {
        __syncthreads();
        *(bf16x8*)&As[ar * 40 + ak]     = a0;
        *(bf16x8*)&As[ar * 40 + ak + 8] = a1;
        *(bf16x8*)&Bs[br * 40 + bk]     = b0;
        __syncthreads();

        if (k0 + 32 < K) {
            a0 = *(const bf16x8*)(aptr + k0 + 32);
            a1 = *(const bf16x8*)(aptr + k0 + 40);
            b0 = *(const bf16x8*)(bptr + k0 + 32);
        }

        bf16x8 af[2], bf[4];
#pragma unroll
        for (int mi = 0; mi < 2; ++mi)
            af[mi] = *(const bf16x8*)&As[(wave * 32 + mi * 16 + l15) * 40 + quad * 8];
#pragma unroll
        for (int ni = 0; ni < 4; ++ni)
            bf[ni] = *(const bf16x8*)&Bs[(ni * 16 + l15) * 40 + quad * 8];
#pragma unroll
        for (int mi = 0; mi < 2; ++mi)
#pragma unroll
            for (int ni = 0; ni < 4; ++ni)
                acc[mi][ni] = __builtin_amdgcn_mfma_f32_16x16x32_bf16(
                    af[mi], bf[ni], acc[mi][ni], 0, 0, 0);
    }

    if (MODE == 2) {
        // ---- V^T epilogue: stage 128(s) x 64(v) accs into LDS as [v][s],
        // then coalesced store to Cv[v][s] with row stride S_LEN.
        __syncthreads();                  // last K-step's LDS reads done
#pragma unroll
        for (int mi = 0; mi < 2; ++mi)
#pragma unroll
            for (int ni = 0; ni < 4; ++ni) {
                const float bv = bias[col0 + ni * 16 + l15];
                const int lrow = wave * 32 + mi * 16 + quad * 4;   // mult of 4
                uint2 uu;
                uu.x = pack_bf16x2((acc[mi][ni][0] + bv) * scale,
                                   (acc[mi][ni][1] + bv) * scale);
                uu.y = pack_bf16x2((acc[mi][ni][2] + bv) * scale,
                                   (acc[mi][ni][3] + bv) * scale);
                *(uint2*)&Ts[(ni * 16 + l15) * 136 + lrow] = uu;
            }
        __syncthreads();
        const int v = tid >> 2, s0 = (tid & 3) * 32;
#pragma unroll
        for (int i = 0; i < 4; ++i) {
            const uint4 d = *(const uint4*)&Ts[v * 136 + s0 + 8 * i];
            *(uint4*)&((ushort*)Cv)[(size_t)(col0 + v) * S_LEN + row0 + s0 + 8 * i] = d;
        }
        return;
    }

#pragma unroll
    for (int mi = 0; mi < 2; ++mi)
#pragma unroll
        for (int ni = 0; ni < 4; ++ni) {
            const int col = col0 + ni * 16 + l15;
            const float bv = bias[col];
#pragma unroll
            for (int reg = 0; reg < 4; ++reg) {
                const int row = row0 + wave * 32 + mi * 16 + quad * 4 + reg;
                const float val = (acc[mi][ni][reg] + bv) * scale;
                if (MODE == 1)
                    ((float*)Cv)[(size_t)row * N + col] = val;
                else
                    ((ushort*)Cv)[(size_t)row * N + col] = f32_to_bf16(val);
            }
        }
}

// O projection (f32 out) standalone
__global__ __launch_bounds__(256) void gemm_o(
        const ushort* __restrict__ A, const ushort* __restrict__ Bt,
        const float* __restrict__ bias, float* __restrict__ Cv, int N, int K) {
    __shared__ ushort smem[128 * 40 + 64 * 40];
    gemm_body_128x64<1>(A, Bt, bias, Cv, smem, smem + 128 * 40, nullptr, N, K, 1.0f);
}

// Q, K, V projections fused in one dispatch via gridDim.z.
// z=0: Q (grid.x 0..31, N=2048); z=1: K, z=2: V (grid.x 0..7 used, N=512).
// V writes V^T directly (MODE 2).
__global__ __launch_bounds__(256) void gemm_qkv(
        const ushort* __restrict__ Xq, const ushort* __restrict__ Xk,
        const ushort* __restrict__ Xv,
        const ushort* __restrict__ Wqt, const ushort* __restrict__ Wkt,
        const ushort* __restrict__ Wvt,
        const float* __restrict__ bq, const float* __restrict__ bk,
        const float* __restrict__ bv,
        ushort* __restrict__ Qb, ushort* __restrict__ Kb,
        ushort* __restrict__ Vtp, int K, float qscale) {
    __shared__ ushort smem[64 * 136];   // 8704 >= 128*40 + 64*40 = 7680
    ushort* As = smem;
    ushort* Bs = smem + 128 * 40;
    const int z = blockIdx.z;
    if (z == 0) {
        gemm_body_128x64<0>(Xq, Wqt, bq, Qb, As, Bs, nullptr, 2048, K, qscale);
    } else if (blockIdx.x < 8) {
        if (z == 1)
            gemm_body_128x64<0>(Xk, Wkt, bk, Kb, As, Bs, nullptr, 512, K, 1.0f);
        else
            gemm_body_128x64<2>(Xv, Wvt, bv, Vtp, As, Bs, smem, 512, K, 1.0f);
    }
}

// ------------------------------------------------------ MFMA flash attention
// Grid (16, 32): block handles q-tiles {bx, 31-bx} of one head sequentially —
// exactly 33 j-tiles per block (perfect causal load balance), 512 blocks.
// 4 waves/block; wave owns a 16-row Q stripe.
//
// SWAPPED-OPERAND version: S^T = mfma(K_frag, Q_frag) puts q in the C-layout
// column (l15) — each lane owns ONE q row. Online-softmax state (m, l) is a
// single scalar per lane; row max/sum = 15 in-lane ops + 2 shfl_xor (16, 32).
// P^T packs into per-wave LDS as [q][key] (8B vector stores) and reads back
// contiguously as the PV B-frag. PV computes O^T = mfma(V^T_frag, P^T_frag);
// V^T LDS tile is already in A-frag layout. Scale (1/sqrt(dk) * log2e) is
// pre-folded into Q; exp = exp2. Defer-max rescale (T13).
__global__ __launch_bounds__(256) void gqa_attn_mfma(
        const ushort* __restrict__ Qb, const ushort* __restrict__ Kb,
        const ushort* __restrict__ Vt, ushort* __restrict__ Ab) {
    __shared__ ushort Ks[64 * 72];       // [key][d]
    __shared__ ushort Vs[64 * 72];       // [d][key]
    __shared__ ushort Ps[4][16 * 72];    // per-wave P^T as [q][key]

    const int h    = blockIdx.y, g = h >> 2;
    const int tid  = threadIdx.x;
    const int lane = tid & 63, wave = tid >> 6;
    const int l15  = lane & 15, quad = lane >> 4;
    const int NT   = S_LEN / 64;         // 32 q-tiles
    const float DEFER_THR = 11.5416f;    // 8 * log2(e)

    // per-thread staging coordinates (fixed across tiles)
    const int srow = tid >> 2, sch = tid & 3;
    const ushort* kbase = Kb + (size_t)srow * (NG * DK) + g * DK + sch * 16;
    const ushort* vbase = Vt + (size_t)(g * 64 + srow) * S_LEN + sch * 16;

    for (int sel = 0; sel < 2; ++sel) {
        const int qt = sel ? (NT - 1 - (int)blockIdx.x) : (int)blockIdx.x;
        const int qr = qt * 64 + wave * 16;      // wave's first q row

        // Q frags (scale pre-folded at projection time), d=0..31 / 32..63
        bf16x8 qa0, qa1;
        {
            const size_t base = (size_t)(qr + l15) * (NH * DK) + (size_t)h * DK + quad * 8;
            qa0 = *(const bf16x8*)&Qb[base];
            qa1 = *(const bf16x8*)&Qb[base + 32];
        }

        f32x4 o[4];                      // O^T: lane = q (l15); rows = d
#pragma unroll
        for (int dt = 0; dt < 4; ++dt) { f32x4 z = {0.f,0.f,0.f,0.f}; o[dt] = z; }
        float m = -1e30f;                // per-lane (per-q) running max, log2 domain
        float l = 0.f;                   // per-lane running sum

        // preload tile 0
        bf16x8 kr0 = *(const bf16x8*)(kbase);
        bf16x8 kr1 = *(const bf16x8*)(kbase + 8);
        bf16x8 vr0 = *(const bf16x8*)(vbase);
        bf16x8 vr1 = *(const bf16x8*)(vbase + 8);

        for (int jt = 0; jt <= qt; ++jt) {
            __syncthreads();             // prior LDS reads complete
            *(bf16x8*)&Ks[srow * 72 + sch * 16]     = kr0;
            *(bf16x8*)&Ks[srow * 72 + sch * 16 + 8] = kr1;
            *(bf16x8*)&Vs[srow * 72 + sch * 16]     = vr0;
            *(bf16x8*)&Vs[srow * 72 + sch * 16 + 8] = vr1;
            __syncthreads();

            // prefetch tile jt+1 (flies during compute below)
            if (jt < qt) {
                const size_t ko = (size_t)(jt + 1) * 64 * (NG * DK);
                const size_t vo = (size_t)(jt + 1) * 64;
                kr0 = *(const bf16x8*)(kbase + ko);
                kr1 = *(const bf16x8*)(kbase + ko + 8);
                vr0 = *(const bf16x8*)(vbase + vo);
                vr1 = *(const bf16x8*)(vbase + vo + 8);
            }

            // S^T = K Q^T : C-layout col = q (l15), row = key (quad*4+r, +16*kt)
            f32x4 s[4];
#pragma unroll
            for (int kt = 0; kt < 4; ++kt) {
                const bf16x8 kb0 = *(const bf16x8*)&Ks[(kt * 16 + l15) * 72 + quad * 8];
                const bf16x8 kb1 = *(const bf16x8*)&Ks[(kt * 16 + l15) * 72 + 32 + quad * 8];
                f32x4 acc = {0.f, 0.f, 0.f, 0.f};
                acc = __builtin_amdgcn_mfma_f32_16x16x32_bf16(kb0, qa0, acc, 0, 0, 0);
                acc = __builtin_amdgcn_mfma_f32_16x16x32_bf16(kb1, qa1, acc, 0, 0, 0);
                s[kt] = acc;
            }

            // causal mask (diagonal tile only; scale already folded into Q)
            if (jt == qt) {
                const int row = wave * 16 + l15;   // q within the 64-row tile
#pragma unroll
                for (int kt = 0; kt < 4; ++kt)
#pragma unroll
                    for (int r = 0; r < 4; ++r) {
                        const int key = kt * 16 + quad * 4 + r;
                        if (key > row) s[kt][r] = -1e30f;
                    }
            }

            // tile max for this q row: 15 in-lane + cross-quad (xor 16, 32)
            float pmax;
            {
                const float t0 = fmaxf(fmaxf(s[0][0], s[0][1]), fmaxf(s[0][2], s[0][3]));
                const float t1 = fmaxf(fmaxf(s[1][0], s[1][1]), fmaxf(s[1][2], s[1][3]));
                const float t2 = fmaxf(fmaxf(s[2][0], s[2][1]), fmaxf(s[2][2], s[2][3]));
                const float t3 = fmaxf(fmaxf(s[3][0], s[3][1]), fmaxf(s[3][2], s[3][3]));
                pmax = fmaxf(fmaxf(t0, t1), fmaxf(t2, t3));
            }
            pmax = fmaxf(pmax, __shfl_xor(pmax, 16, 64));
            pmax = fmaxf(pmax, __shfl_xor(pmax, 32, 64));

            // defer-max: only rescale when the tile max grew past threshold
            if (!__all(pmax - m <= DEFER_THR)) {
                const float mnew  = fmaxf(m, pmax);
                const float alpha = __builtin_amdgcn_exp2f(m - mnew);
                l *= alpha;
#pragma unroll
                for (int dt = 0; dt < 4; ++dt)
#pragma unroll
                    for (int r = 0; r < 4; ++r) o[dt][r] *= alpha;
                m = mnew;
            }

            float p[4][4];
#pragma unroll
            for (int kt = 0; kt < 4; ++kt)
#pragma unroll
                for (int r = 0; r < 4; ++r)
                    p[kt][r] = __builtin_amdgcn_exp2f(s[kt][r] - m);

            float rsum;
            {
                const float u0 = (p[0][0] + p[0][1]) + (p[0][2] + p[0][3]);
                const float u1 = (p[1][0] + p[1][1]) + (p[1][2] + p[1][3]);
                const float u2 = (p[2][0] + p[2][1]) + (p[2][2] + p[2][3]);
                const float u3 = (p[3][0] + p[3][1]) + (p[3][2] + p[3][3]);
                rsum = (u0 + u1) + (u2 + u3);
            }
            rsum += __shfl_xor(rsum, 16, 64);
            rsum += __shfl_xor(rsum, 32, 64);
            l += rsum;

            // P^T -> per-wave LDS [q][key]: 8B vector stores, contiguous keys
            ushort* Pw = &Ps[wave][0];
#pragma unroll
            for (int kt = 0; kt < 4; ++kt) {
                uint2 uu;
                uu.x = pack_bf16x2(p[kt][0], p[kt][1]);
                uu.y = pack_bf16x2(p[kt][2], p[kt][3]);
                *(uint2*)&Pw[l15 * 72 + kt * 16 + quad * 4] = uu;
            }
            const bf16x8 pa0 = *(const bf16x8*)&Pw[l15 * 72 + quad * 8];
            const bf16x8 pa1 = *(const bf16x8*)&Pw[l15 * 72 + 32 + quad * 8];

            // O^T += V^T P^T : A = V^T tile (already [d][key] in LDS), B = P^T
#pragma unroll
            for (int dt = 0; dt < 4; ++dt) {
                const bf16x8 vb0 = *(const bf16x8*)&Vs[(dt * 16 + l15) * 72 + quad * 8];
                const bf16x8 vb1 = *(const bf16x8*)&Vs[(dt * 16 + l15) * 72 + 32 + quad * 8];
                o[dt] = __builtin_amdgcn_mfma_f32_16x16x32_bf16(vb0, pa0, o[dt], 0, 0, 0);
                o[dt] = __builtin_amdgcn_mfma_f32_16x16x32_bf16(vb1, pa1, o[dt], 0, 0, 0);
            }
        }

        // epilogue: lane holds O^T[d = dt*16 + quad*4 + r][q = l15]
        const float invl = 1.0f / l;
#pragma unroll
        for (int dt = 0; dt < 4; ++dt) {
            uint2 uu;
            uu.x = pack_bf16x2(o[dt][0] * invl, o[dt][1] * invl);
            uu.y = pack_bf16x2(o[dt][2] * invl, o[dt][3] * invl);
            *(uint2*)&Ab[(size_t)(qr + l15) * (NH * DV) + (size_t)h * DV + dt * 16 + quad * 4] = uu;
        }
    }
}

// ---------------------------------------------------------------------------
extern "C" void kernel_launch(void* const* d_in, const int* in_sizes, int n_in,
                              void* d_out, int out_size, void* d_ws, size_t ws_size,
                              hipStream_t stream) {
    const float* queries = (const float*)d_in[0];
    const float* keys    = (const float*)d_in[1];
    const float* values  = (const float*)d_in[2];
    const float* Wq      = (const float*)d_in[3];
    const float* bq      = (const float*)d_in[4];
    const float* Wk      = (const float*)d_in[5];
    const float* bk      = (const float*)d_in[6];
    const float* Wv      = (const float*)d_in[7];
    const float* bv      = (const float*)d_in[8];
    const float* Wo      = (const float*)d_in[9];
    const float* bo      = (const float*)d_in[10];
    float* out = (float*)d_out;

    const size_t MB = 1024 * 1024;
    unsigned char* w = (unsigned char*)d_ws;
    ushort* Xq  = (ushort*)(w + 0 * MB);    // [2048][2048] bf16
    ushort* Xk  = (ushort*)(w + 8 * MB);
    ushort* Xv  = (ushort*)(w + 16 * MB);
    ushort* Wqt = (ushort*)(w + 24 * MB);   // [2048][2048]
    ushort* Wkt = (ushort*)(w + 32 * MB);   // [512][2048]
    ushort* Wvt = (ushort*)(w + 34 * MB);
    ushort* Wot = (ushort*)(w + 36 * MB);   // [2048][2048]
    ushort* Qb  = (ushort*)(w + 44 * MB);   // [2048][2048]
    ushort* Kb  = (ushort*)(w + 52 * MB);   // [2048][512]
    ushort* Vtp = (ushort*)(w + 54 * MB);   // V^T [512][2048] (written directly)
    ushort* Ab  = (ushort*)(w + 56 * MB);   // [2048][2048]

    const int n8 = (S_LEN * DMODEL) / 8;
    cast3_f32_to_bf16<<<dim3(1024, 1, 3), 256, 0, stream>>>(
        queries, keys, values, Xq, Xk, Xv, n8);

    dim3 tb(32, 8);
    transpose_cast4<<<dim3(160, 64), tb, 0, stream>>>(
        Wq, Wk, Wv, Wo, Wqt, Wkt, Wvt, Wot);

    // Q/K/V projections in one dispatch; V written as V^T; softmax scale
    // (1/sqrt(dk) * log2(e)) folded into Q.
    const float QSCALE = 0.125f * 1.44269504f;
    gemm_qkv<<<dim3(32, 16, 3), 256, 0, stream>>>(
        Xq, Xk, Xv, Wqt, Wkt, Wvt, bq, bk, bv, Qb, Kb, Vtp, DMODEL, QSCALE);

    // attention: paired q-tiles for perfect causal balance
    gqa_attn_mfma<<<dim3(16, 32), 256, 0, stream>>>(Qb, Kb, Vtp, Ab);

    // O projection: [2048,2048] @ [2048,2048] -> f32 out
    gemm_o<<<dim3(2048 / 64, 2048 / 128), 256, 0, stream>>>(
        Ab, Wot, bo, out, 2048, DMODEL);
}

// Round 4
// 291.667 us; speedup vs baseline: 1.0961x; 1.0961x over previous
//
#include <hip/hip_runtime.h>
#include <hip/hip_bf16.h>

#define S_LEN  2048
#define DMODEL 2048
#define NH     32
#define NG     8
#define DK     64
#define DV     64

typedef short bf16x8 __attribute__((ext_vector_type(8)));
typedef float f32x4  __attribute__((ext_vector_type(4)));

__device__ __forceinline__ ushort f32_to_bf16(float f) {
    uint u = __float_as_uint(f);
    return (ushort)((u + 0x7fffu + ((u >> 16) & 1u)) >> 16);   // RNE
}
__device__ __forceinline__ float bf16_to_f32(ushort h) {
    return __uint_as_float(((uint)h) << 16);
}
__device__ __forceinline__ uint pack_bf16x2(float a, float b) {
    return (uint)f32_to_bf16(a) | ((uint)f32_to_bf16(b) << 16);
}

// ------------------------------------------- fused cast f32->bf16 (q,k,v in one)
__global__ void cast3_f32_to_bf16(const float* __restrict__ q,
                                  const float* __restrict__ k,
                                  const float* __restrict__ v,
                                  ushort* __restrict__ xq,
                                  ushort* __restrict__ xk,
                                  ushort* __restrict__ xv, int n8) {
    const float* in  = blockIdx.z == 0 ? q  : (blockIdx.z == 1 ? k  : v);
    ushort*      out = blockIdx.z == 0 ? xq : (blockIdx.z == 1 ? xk : xv);
    int i = blockIdx.x * blockDim.x + threadIdx.x;
    const int stride = gridDim.x * blockDim.x;
    for (; i < n8; i += stride) {
        const float4 a = ((const float4*)in)[2 * i];
        const float4 b = ((const float4*)in)[2 * i + 1];
        uint4 o;
        o.x = (uint)f32_to_bf16(a.x) | ((uint)f32_to_bf16(a.y) << 16);
        o.y = (uint)f32_to_bf16(a.z) | ((uint)f32_to_bf16(a.w) << 16);
        o.z = (uint)f32_to_bf16(b.x) | ((uint)f32_to_bf16(b.y) << 16);
        o.w = (uint)f32_to_bf16(b.z) | ((uint)f32_to_bf16(b.w) << 16);
        ((uint4*)out)[i] = o;
    }
}

// ---------------------- fused W[K][N] f32 -> Wt[N][K] bf16 for all four weights
// grid.x block ranges: [0,64) Wq, [64,80) Wk, [80,96) Wv, [96,160) Wo. K=2048.
__global__ void transpose_cast4(const float* __restrict__ Wq,
                                const float* __restrict__ Wk,
                                const float* __restrict__ Wv,
                                const float* __restrict__ Wo,
                                ushort* __restrict__ Wqt, ushort* __restrict__ Wkt,
                                ushort* __restrict__ Wvt, ushort* __restrict__ Wot) {
    __shared__ float t[32][33];
    int bx = blockIdx.x;
    const float* W; ushort* Wt; int N;
    if (bx < 64)      { W = Wq; Wt = Wqt; N = 2048; }
    else if (bx < 80) { W = Wk; Wt = Wkt; N = 512;  bx -= 64; }
    else if (bx < 96) { W = Wv; Wt = Wvt; N = 512;  bx -= 80; }
    else              { W = Wo; Wt = Wot; N = 2048; bx -= 96; }
    const int n0 = bx * 32, k0 = blockIdx.y * 32;
    const int tx = threadIdx.x, ty = threadIdx.y;   // 32 x 8
#pragma unroll
    for (int i = 0; i < 4; ++i)
        t[ty + 8 * i][tx] = W[(size_t)(k0 + ty + 8 * i) * N + n0 + tx];
    __syncthreads();
#pragma unroll
    for (int i = 0; i < 4; ++i)
        Wt[(size_t)(n0 + ty + 8 * i) * 2048 + k0 + tx] = f32_to_bf16(t[tx][ty + 8 * i]);
}

// ------------------------------------------------------------- bf16 MFMA GEMM
// C[M][N] = (A[M][K] @ Bt[N][K]^T + bias) * scale.  128(M)x64(N) tile, 4 waves
// stacked in M (each: 32 rows x 64 cols = 2x4 frags of mfma_f32_16x16x32_bf16).
// LDS row stride 40 shorts (2-way bank alias only). Register-prefetch
// pipeline: next k-tile's global loads issue before compute.
// MODE: 0 = bf16 C, 1 = f32 C, 2 = bf16 C^T (V^T, output stride S_LEN) via LDS.
template <int MODE>
__device__ __forceinline__ void gemm_body_128x64(
        const ushort* __restrict__ A, const ushort* __restrict__ Bt,
        const float* __restrict__ bias, void* __restrict__ Cv,
        ushort* As, ushort* Bs, ushort* Ts, int N, int K, float scale,
        int bx, int by) {
    const int tid  = threadIdx.x;
    const int lane = tid & 63, wave = tid >> 6;
    const int l15 = lane & 15, quad = lane >> 4;
    const int row0 = by * 128, col0 = bx * 64;

    f32x4 acc[2][4];
#pragma unroll
    for (int i = 0; i < 2; ++i)
#pragma unroll
        for (int j = 0; j < 4; ++j) { f32x4 z = {0.f,0.f,0.f,0.f}; acc[i][j] = z; }

    // staging coords: A 128x32 (2 b128/thread), B 64x32 (1 b128/thread)
    const int ar = tid >> 1, ak = (tid & 1) * 16;
    const int br = tid >> 2, bk = (tid & 3) * 8;
    const ushort* aptr = A  + (size_t)(row0 + ar) * K + ak;
    const ushort* bptr = Bt + (size_t)(col0 + br) * K + bk;

    bf16x8 a0 = *(const bf16x8*)(aptr);
    bf16x8 a1 = *(const bf16x8*)(aptr + 8);
    bf16x8 b0 = *(const bf16x8*)(bptr);

    for (int k0 = 0; k0 < K; k0 += 32) {
        __syncthreads();
        *(bf16x8*)&As[ar * 40 + ak]     = a0;
        *(bf16x8*)&As[ar * 40 + ak + 8] = a1;
        *(bf16x8*)&Bs[br * 40 + bk]     = b0;
        __syncthreads();

        if (k0 + 32 < K) {
            a0 = *(const bf16x8*)(aptr + k0 + 32);
            a1 = *(const bf16x8*)(aptr + k0 + 40);
            b0 = *(const bf16x8*)(bptr + k0 + 32);
        }

        bf16x8 af[2], bf[4];
#pragma unroll
        for (int mi = 0; mi < 2; ++mi)
            af[mi] = *(const bf16x8*)&As[(wave * 32 + mi * 16 + l15) * 40 + quad * 8];
#pragma unroll
        for (int ni = 0; ni < 4; ++ni)
            bf[ni] = *(const bf16x8*)&Bs[(ni * 16 + l15) * 40 + quad * 8];
#pragma unroll
        for (int mi = 0; mi < 2; ++mi)
#pragma unroll
            for (int ni = 0; ni < 4; ++ni)
                acc[mi][ni] = __builtin_amdgcn_mfma_f32_16x16x32_bf16(
                    af[mi], bf[ni], acc[mi][ni], 0, 0, 0);
    }

    if (MODE == 2) {
        // ---- V^T epilogue: stage 128(s) x 64(v) accs into LDS as [v][s],
        // then coalesced store to Cv[v][s] with row stride S_LEN.
        __syncthreads();                  // last K-step's LDS reads done
#pragma unroll
        for (int mi = 0; mi < 2; ++mi)
#pragma unroll
            for (int ni = 0; ni < 4; ++ni) {
                const float bv = bias[col0 + ni * 16 + l15];
                const int lrow = wave * 32 + mi * 16 + quad * 4;   // mult of 4
                uint2 uu;
                uu.x = pack_bf16x2((acc[mi][ni][0] + bv) * scale,
                                   (acc[mi][ni][1] + bv) * scale);
                uu.y = pack_bf16x2((acc[mi][ni][2] + bv) * scale,
                                   (acc[mi][ni][3] + bv) * scale);
                *(uint2*)&Ts[(ni * 16 + l15) * 136 + lrow] = uu;
            }
        __syncthreads();
        const int v = tid >> 2, s0 = (tid & 3) * 32;
#pragma unroll
        for (int i = 0; i < 4; ++i) {
            const uint4 d = *(const uint4*)&Ts[v * 136 + s0 + 8 * i];
            *(uint4*)&((ushort*)Cv)[(size_t)(col0 + v) * S_LEN + row0 + s0 + 8 * i] = d;
        }
        return;
    }

#pragma unroll
    for (int mi = 0; mi < 2; ++mi)
#pragma unroll
        for (int ni = 0; ni < 4; ++ni) {
            const int col = col0 + ni * 16 + l15;
            const float bv = bias[col];
#pragma unroll
            for (int reg = 0; reg < 4; ++reg) {
                const int row = row0 + wave * 32 + mi * 16 + quad * 4 + reg;
                const float val = (acc[mi][ni][reg] + bv) * scale;
                if (MODE == 1)
                    ((float*)Cv)[(size_t)row * N + col] = val;
                else
                    ((ushort*)Cv)[(size_t)row * N + col] = f32_to_bf16(val);
            }
        }
}

// XCD-aware 2D-chunk decode for 512-block GEMMs (32 col-tiles x 16 row-tiles).
// Dispatch round-robins blocks over 8 XCDs (xcd = d & 7); give each XCD an
// 8x8 tile rect so it touches 8 A-panels (4 MB) + 8 B-panels (2 MB) ~ L2-sized.
__device__ __forceinline__ void xcd_decode_32x16(int d, int& bx, int& by) {
    const int xcd = d & 7, i = d >> 3;          // i in [0,64)
    bx = (xcd & 3) * 8 + (i & 7);
    by = (xcd >> 2) * 8 + (i >> 3);
}

// Q projection: [2048,2048]x[2048,2048], bf16 out, scale folded
__global__ __launch_bounds__(256) void gemm_q(
        const ushort* __restrict__ A, const ushort* __restrict__ Bt,
        const float* __restrict__ bias, ushort* __restrict__ Cv, int K,
        float scale) {
    __shared__ ushort smem[128 * 40 + 64 * 40];
    int bx, by; xcd_decode_32x16(blockIdx.x, bx, by);
    gemm_body_128x64<0>(A, Bt, bias, Cv, smem, smem + 128 * 40, nullptr,
                        2048, K, scale, bx, by);
}

// O projection: f32 out
__global__ __launch_bounds__(256) void gemm_o(
        const ushort* __restrict__ A, const ushort* __restrict__ Bt,
        const float* __restrict__ bias, float* __restrict__ Cv, int K) {
    __shared__ ushort smem[128 * 40 + 64 * 40];
    int bx, by; xcd_decode_32x16(blockIdx.x, bx, by);
    gemm_body_128x64<1>(A, Bt, bias, Cv, smem, smem + 128 * 40, nullptr,
                        2048, K, 1.0f, bx, by);
}

// K and V projections fused via gridDim.z; V writes V^T directly (MODE 2).
__global__ __launch_bounds__(256) void gemm_kv(
        const ushort* __restrict__ Xk, const ushort* __restrict__ Xv,
        const ushort* __restrict__ Wkt, const ushort* __restrict__ Wvt,
        const float* __restrict__ bk, const float* __restrict__ bv,
        ushort* __restrict__ Kb, ushort* __restrict__ Vtp, int K) {
    __shared__ ushort smem[64 * 136];   // 8704 >= 128*40 + 64*40 = 7680
    ushort* As = smem;
    ushort* Bs = smem + 128 * 40;
    if (blockIdx.z == 0)
        gemm_body_128x64<0>(Xk, Wkt, bk, Kb, As, Bs, nullptr, 512, K, 1.0f,
                            blockIdx.x, blockIdx.y);
    else
        gemm_body_128x64<2>(Xv, Wvt, bv, Vtp, As, Bs, smem, 512, K, 1.0f,
                            blockIdx.x, blockIdx.y);
}

// ------------------------------------------------------ MFMA flash attention
// Grid (16, 32): block handles q-tiles {bx, 31-bx} of one head sequentially —
// exactly 33 j-tiles per block (perfect causal load balance), 512 blocks.
// 4 waves/block; wave owns a 16-row Q stripe.
//
// SWAPPED-OPERAND version: S^T = mfma(K_frag, Q_frag) puts q in the C-layout
// column (l15) — each lane owns ONE q row. Online-softmax state (m, l) is a
// single scalar per lane; row max/sum = 15 in-lane ops + 2 shfl_xor (16, 32).
// P^T packs into per-wave LDS as [q][key] (8B vector stores) and reads back
// contiguously as the PV B-frag. PV computes O^T = mfma(V^T_frag, P^T_frag);
// V^T LDS tile is already in A-frag layout. Scale (1/sqrt(dk) * log2e) is
// pre-folded into Q; exp = exp2. Defer-max rescale (T13).
__global__ __launch_bounds__(256) void gqa_attn_mfma(
        const ushort* __restrict__ Qb, const ushort* __restrict__ Kb,
        const ushort* __restrict__ Vt, ushort* __restrict__ Ab) {
    __shared__ ushort Ks[64 * 72];       // [key][d]
    __shared__ ushort Vs[64 * 72];       // [d][key]
    __shared__ ushort Ps[4][16 * 72];    // per-wave P^T as [q][key]

    const int h    = blockIdx.y, g = h >> 2;
    const int tid  = threadIdx.x;
    const int lane = tid & 63, wave = tid >> 6;
    const int l15  = lane & 15, quad = lane >> 4;
    const int NT   = S_LEN / 64;         // 32 q-tiles
    const float DEFER_THR = 11.5416f;    // 8 * log2(e)

    // per-thread staging coordinates (fixed across tiles)
    const int srow = tid >> 2, sch = tid & 3;
    const ushort* kbase = Kb + (size_t)srow * (NG * DK) + g * DK + sch * 16;
    const ushort* vbase = Vt + (size_t)(g * 64 + srow) * S_LEN + sch * 16;

    for (int sel = 0; sel < 2; ++sel) {
        const int qt = sel ? (NT - 1 - (int)blockIdx.x) : (int)blockIdx.x;
        const int qr = qt * 64 + wave * 16;      // wave's first q row

        // Q frags (scale pre-folded at projection time), d=0..31 / 32..63
        bf16x8 qa0, qa1;
        {
            const size_t base = (size_t)(qr + l15) * (NH * DK) + (size_t)h * DK + quad * 8;
            qa0 = *(const bf16x8*)&Qb[base];
            qa1 = *(const bf16x8*)&Qb[base + 32];
        }

        f32x4 o[4];                      // O^T: lane = q (l15); rows = d
#pragma unroll
        for (int dt = 0; dt < 4; ++dt) { f32x4 z = {0.f,0.f,0.f,0.f}; o[dt] = z; }
        float m = -1e30f;                // per-lane (per-q) running max, log2 domain
        float l = 0.f;                   // per-lane running sum

        // preload tile 0
        bf16x8 kr0 = *(const bf16x8*)(kbase);
        bf16x8 kr1 = *(const bf16x8*)(kbase + 8);
        bf16x8 vr0 = *(const bf16x8*)(vbase);
        bf16x8 vr1 = *(const bf16x8*)(vbase + 8);

        for (int jt = 0; jt <= qt; ++jt) {
            __syncthreads();             // prior LDS reads complete
            *(bf16x8*)&Ks[srow * 72 + sch * 16]     = kr0;
            *(bf16x8*)&Ks[srow * 72 + sch * 16 + 8] = kr1;
            *(bf16x8*)&Vs[srow * 72 + sch * 16]     = vr0;
            *(bf16x8*)&Vs[srow * 72 + sch * 16 + 8] = vr1;
            __syncthreads();

            // prefetch tile jt+1 (flies during compute below)
            if (jt < qt) {
                const size_t ko = (size_t)(jt + 1) * 64 * (NG * DK);
                const size_t vo = (size_t)(jt + 1) * 64;
                kr0 = *(const bf16x8*)(kbase + ko);
                kr1 = *(const bf16x8*)(kbase + ko + 8);
                vr0 = *(const bf16x8*)(vbase + vo);
                vr1 = *(const bf16x8*)(vbase + vo + 8);
            }

            // S^T = K Q^T : C-layout col = q (l15), row = key (quad*4+r, +16*kt)
            f32x4 s[4];
#pragma unroll
            for (int kt = 0; kt < 4; ++kt) {
                const bf16x8 kb0 = *(const bf16x8*)&Ks[(kt * 16 + l15) * 72 + quad * 8];
                const bf16x8 kb1 = *(const bf16x8*)&Ks[(kt * 16 + l15) * 72 + 32 + quad * 8];
                f32x4 acc = {0.f, 0.f, 0.f, 0.f};
                acc = __builtin_amdgcn_mfma_f32_16x16x32_bf16(kb0, qa0, acc, 0, 0, 0);
                acc = __builtin_amdgcn_mfma_f32_16x16x32_bf16(kb1, qa1, acc, 0, 0, 0);
                s[kt] = acc;
            }

            // causal mask (diagonal tile only; scale already folded into Q)
            if (jt == qt) {
                const int row = wave * 16 + l15;   // q within the 64-row tile
#pragma unroll
                for (int kt = 0; kt < 4; ++kt)
#pragma unroll
                    for (int r = 0; r < 4; ++r) {
                        const int key = kt * 16 + quad * 4 + r;
                        if (key > row) s[kt][r] = -1e30f;
                    }
            }

            // tile max for this q row: 15 in-lane + cross-quad (xor 16, 32)
            float pmax;
            {
                const float t0 = fmaxf(fmaxf(s[0][0], s[0][1]), fmaxf(s[0][2], s[0][3]));
                const float t1 = fmaxf(fmaxf(s[1][0], s[1][1]), fmaxf(s[1][2], s[1][3]));
                const float t2 = fmaxf(fmaxf(s[2][0], s[2][1]), fmaxf(s[2][2], s[2][3]));
                const float t3 = fmaxf(fmaxf(s[3][0], s[3][1]), fmaxf(s[3][2], s[3][3]));
                pmax = fmaxf(fmaxf(t0, t1), fmaxf(t2, t3));
            }
            pmax = fmaxf(pmax, __shfl_xor(pmax, 16, 64));
            pmax = fmaxf(pmax, __shfl_xor(pmax, 32, 64));

            // defer-max: only rescale when the tile max grew past threshold
            if (!__all(pmax - m <= DEFER_THR)) {
                const float mnew  = fmaxf(m, pmax);
                const float alpha = __builtin_amdgcn_exp2f(m - mnew);
                l *= alpha;
#pragma unroll
                for (int dt = 0; dt < 4; ++dt)
#pragma unroll
                    for (int r = 0; r < 4; ++r) o[dt][r] *= alpha;
                m = mnew;
            }

            float p[4][4];
#pragma unroll
            for (int kt = 0; kt < 4; ++kt)
#pragma unroll
                for (int r = 0; r < 4; ++r)
                    p[kt][r] = __builtin_amdgcn_exp2f(s[kt][r] - m);

            float rsum;
            {
                const float u0 = (p[0][0] + p[0][1]) + (p[0][2] + p[0][3]);
                const float u1 = (p[1][0] + p[1][1]) + (p[1][2] + p[1][3]);
                const float u2 = (p[2][0] + p[2][1]) + (p[2][2] + p[2][3]);
                const float u3 = (p[3][0] + p[3][1]) + (p[3][2] + p[3][3]);
                rsum = (u0 + u1) + (u2 + u3);
            }
            rsum += __shfl_xor(rsum, 16, 64);
            rsum += __shfl_xor(rsum, 32, 64);
            l += rsum;

            // P^T -> per-wave LDS [q][key]: 8B vector stores, contiguous keys
            ushort* Pw = &Ps[wave][0];
#pragma unroll
            for (int kt = 0; kt < 4; ++kt) {
                uint2 uu;
                uu.x = pack_bf16x2(p[kt][0], p[kt][1]);
                uu.y = pack_bf16x2(p[kt][2], p[kt][3]);
                *(uint2*)&Pw[l15 * 72 + kt * 16 + quad * 4] = uu;
            }
            const bf16x8 pa0 = *(const bf16x8*)&Pw[l15 * 72 + quad * 8];
            const bf16x8 pa1 = *(const bf16x8*)&Pw[l15 * 72 + 32 + quad * 8];

            // O^T += V^T P^T : A = V^T tile (already [d][key] in LDS), B = P^T
#pragma unroll
            for (int dt = 0; dt < 4; ++dt) {
                const bf16x8 vb0 = *(const bf16x8*)&Vs[(dt * 16 + l15) * 72 + quad * 8];
                const bf16x8 vb1 = *(const bf16x8*)&Vs[(dt * 16 + l15) * 72 + 32 + quad * 8];
                o[dt] = __builtin_amdgcn_mfma_f32_16x16x32_bf16(vb0, pa0, o[dt], 0, 0, 0);
                o[dt] = __builtin_amdgcn_mfma_f32_16x16x32_bf16(vb1, pa1, o[dt], 0, 0, 0);
            }
        }

        // epilogue: lane holds O^T[d = dt*16 + quad*4 + r][q = l15]
        const float invl = 1.0f / l;
#pragma unroll
        for (int dt = 0; dt < 4; ++dt) {
            uint2 uu;
            uu.x = pack_bf16x2(o[dt][0] * invl, o[dt][1] * invl);
            uu.y = pack_bf16x2(o[dt][2] * invl, o[dt][3] * invl);
            *(uint2*)&Ab[(size_t)(qr + l15) * (NH * DV) + (size_t)h * DV + dt * 16 + quad * 4] = uu;
        }
    }
}

// ---------------------------------------------------------------------------
extern "C" void kernel_launch(void* const* d_in, const int* in_sizes, int n_in,
                              void* d_out, int out_size, void* d_ws, size_t ws_size,
                              hipStream_t stream) {
    const float* queries = (const float*)d_in[0];
    const float* keys    = (const float*)d_in[1];
    const float* values  = (const float*)d_in[2];
    const float* Wq      = (const float*)d_in[3];
    const float* bq      = (const float*)d_in[4];
    const float* Wk      = (const float*)d_in[5];
    const float* bk      = (const float*)d_in[6];
    const float* Wv      = (const float*)d_in[7];
    const float* bv      = (const float*)d_in[8];
    const float* Wo      = (const float*)d_in[9];
    const float* bo      = (const float*)d_in[10];
    float* out = (float*)d_out;

    const size_t MB = 1024 * 1024;
    unsigned char* w = (unsigned char*)d_ws;
    ushort* Xq  = (ushort*)(w + 0 * MB);    // [2048][2048] bf16
    ushort* Xk  = (ushort*)(w + 8 * MB);
    ushort* Xv  = (ushort*)(w + 16 * MB);
    ushort* Wqt = (ushort*)(w + 24 * MB);   // [2048][2048]
    ushort* Wkt = (ushort*)(w + 32 * MB);   // [512][2048]
    ushort* Wvt = (ushort*)(w + 34 * MB);
    ushort* Wot = (ushort*)(w + 36 * MB);   // [2048][2048]
    ushort* Qb  = (ushort*)(w + 44 * MB);   // [2048][2048]
    ushort* Kb  = (ushort*)(w + 52 * MB);   // [2048][512]
    ushort* Vtp = (ushort*)(w + 54 * MB);   // V^T [512][2048] (written directly)
    ushort* Ab  = (ushort*)(w + 56 * MB);   // [2048][2048]

    const int n8 = (S_LEN * DMODEL) / 8;
    cast3_f32_to_bf16<<<dim3(1024, 1, 3), 256, 0, stream>>>(
        queries, keys, values, Xq, Xk, Xv, n8);

    dim3 tb(32, 8);
    transpose_cast4<<<dim3(160, 64), tb, 0, stream>>>(
        Wq, Wk, Wv, Wo, Wqt, Wkt, Wvt, Wot);

    // Q projection (XCD-swizzled); softmax scale * log2(e) folded into Q
    const float QSCALE = 0.125f * 1.44269504f;
    gemm_q<<<512, 256, 0, stream>>>(Xq, Wqt, bq, Qb, DMODEL, QSCALE);

    // K and V projections fused (z=0: K, z=1: V -> V^T direct)
    gemm_kv<<<dim3(8, 16, 2), 256, 0, stream>>>(
        Xk, Xv, Wkt, Wvt, bk, bv, Kb, Vtp, DMODEL);

    // attention: paired q-tiles for perfect causal balance
    gqa_attn_mfma<<<dim3(16, 32), 256, 0, stream>>>(Qb, Kb, Vtp, Ab);

    // O projection (XCD-swizzled): [2048,2048] @ [2048,2048] -> f32 out
    gemm_o<<<512, 256, 0, stream>>>(Ab, Wot, bo, out, DMODEL);
}

// Round 6
// 286.951 us; speedup vs baseline: 1.1142x; 1.0164x over previous
//
#include <hip/hip_runtime.h>
#include <hip/hip_bf16.h>

#define S_LEN  2048
#define DMODEL 2048
#define NH     32
#define NG     8
#define DK     64
#define DV     64

typedef short bf16x8 __attribute__((ext_vector_type(8)));
typedef float f32x4  __attribute__((ext_vector_type(4)));

__device__ __forceinline__ ushort f32_to_bf16(float f) {
    uint u = __float_as_uint(f);
    return (ushort)((u + 0x7fffu + ((u >> 16) & 1u)) >> 16);   // RNE
}
__device__ __forceinline__ float bf16_to_f32(ushort h) {
    return __uint_as_float(((uint)h) << 16);
}
__device__ __forceinline__ uint pack_bf16x2(float a, float b) {
    return (uint)f32_to_bf16(a) | ((uint)f32_to_bf16(b) << 16);
}

// ------------------------------------------- fused cast f32->bf16 (q,k,v in one)
__global__ void cast3_f32_to_bf16(const float* __restrict__ q,
                                  const float* __restrict__ k,
                                  const float* __restrict__ v,
                                  ushort* __restrict__ xq,
                                  ushort* __restrict__ xk,
                                  ushort* __restrict__ xv, int n8) {
    const float* in  = blockIdx.z == 0 ? q  : (blockIdx.z == 1 ? k  : v);
    ushort*      out = blockIdx.z == 0 ? xq : (blockIdx.z == 1 ? xk : xv);
    int i = blockIdx.x * blockDim.x + threadIdx.x;
    const int stride = gridDim.x * blockDim.x;
    for (; i < n8; i += stride) {
        const float4 a = ((const float4*)in)[2 * i];
        const float4 b = ((const float4*)in)[2 * i + 1];
        uint4 o;
        o.x = (uint)f32_to_bf16(a.x) | ((uint)f32_to_bf16(a.y) << 16);
        o.y = (uint)f32_to_bf16(a.z) | ((uint)f32_to_bf16(a.w) << 16);
        o.z = (uint)f32_to_bf16(b.x) | ((uint)f32_to_bf16(b.y) << 16);
        o.w = (uint)f32_to_bf16(b.z) | ((uint)f32_to_bf16(b.w) << 16);
        ((uint4*)out)[i] = o;
    }
}

// ---------------------- fused W[K][N] f32 -> Wt[N][K] bf16 for all four weights
// grid.x block ranges: [0,64) Wq, [64,80) Wk, [80,96) Wv, [96,160) Wo. K=2048.
__global__ void transpose_cast4(const float* __restrict__ Wq,
                                const float* __restrict__ Wk,
                                const float* __restrict__ Wv,
                                const float* __restrict__ Wo,
                                ushort* __restrict__ Wqt, ushort* __restrict__ Wkt,
                                ushort* __restrict__ Wvt, ushort* __restrict__ Wot) {
    __shared__ float t[32][33];
    int bx = blockIdx.x;
    const float* W; ushort* Wt; int N;
    if (bx < 64)      { W = Wq; Wt = Wqt; N = 2048; }
    else if (bx < 80) { W = Wk; Wt = Wkt; N = 512;  bx -= 64; }
    else if (bx < 96) { W = Wv; Wt = Wvt; N = 512;  bx -= 80; }
    else              { W = Wo; Wt = Wot; N = 2048; bx -= 96; }
    const int n0 = bx * 32, k0 = blockIdx.y * 32;
    const int tx = threadIdx.x, ty = threadIdx.y;   // 32 x 8
#pragma unroll
    for (int i = 0; i < 4; ++i)
        t[ty + 8 * i][tx] = W[(size_t)(k0 + ty + 8 * i) * N + n0 + tx];
    __syncthreads();
#pragma unroll
    for (int i = 0; i < 4; ++i)
        Wt[(size_t)(n0 + ty + 8 * i) * 2048 + k0 + tx] = f32_to_bf16(t[tx][ty + 8 * i]);
}

// ------------------------------------------------------------- bf16 MFMA GEMM
// C[M][N] = (A[M][K] @ Bt[N][K]^T + bias) * scale.  128(M)x64(N) tile, 4 waves
// stacked in M (each: 32 rows x 64 cols = 2x4 frags of mfma_f32_16x16x32_bf16).
// LDS row stride 40 shorts (2-way bank alias only). Register-prefetch
// pipeline: next k-tile's global loads issue before compute.
// MODE: 0 = bf16 C, 1 = f32 C, 2 = bf16 C^T (V^T, output stride S_LEN) via LDS.
template <int MODE>
__device__ __forceinline__ void gemm_body_128x64(
        const ushort* __restrict__ A, const ushort* __restrict__ Bt,
        const float* __restrict__ bias, void* __restrict__ Cv,
        ushort* As, ushort* Bs, ushort* Ts, int N, int K, float scale,
        int bx, int by) {
    const int tid  = threadIdx.x;
    const int lane = tid & 63, wave = tid >> 6;
    const int l15 = lane & 15, quad = lane >> 4;
    const int row0 = by * 128, col0 = bx * 64;

    f32x4 acc[2][4];
#pragma unroll
    for (int i = 0; i < 2; ++i)
#pragma unroll
        for (int j = 0; j < 4; ++j) { f32x4 z = {0.f,0.f,0.f,0.f}; acc[i][j] = z; }

    // staging coords: A 128x32 (2 b128/thread), B 64x32 (1 b128/thread)
    const int ar = tid >> 1, ak = (tid & 1) * 16;
    const int br = tid >> 2, bk = (tid & 3) * 8;
    const ushort* aptr = A  + (size_t)(row0 + ar) * K + ak;
    const ushort* bptr = Bt + (size_t)(col0 + br) * K + bk;

    bf16x8 a0 = *(const bf16x8*)(aptr);
    bf16x8 a1 = *(const bf16x8*)(aptr + 8);
    bf16x8 b0 = *(const bf16x8*)(bptr);

    for (int k0 = 0; k0 < K; k0 += 32) {
        __syncthreads();
        *(bf16x8*)&As[ar * 40 + ak]     = a0;
        *(bf16x8*)&As[ar * 40 + ak + 8] = a1;
        *(bf16x8*)&Bs[br * 40 + bk]     = b0;
        __syncthreads();

        if (k0 + 32 < K) {
            a0 = *(const bf16x8*)(aptr + k0 + 32);
            a1 = *(const bf16x8*)(aptr + k0 + 40);
            b0 = *(const bf16x8*)(bptr + k0 + 32);
        }

        bf16x8 af[2], bf[4];
#pragma unroll
        for (int mi = 0; mi < 2; ++mi)
            af[mi] = *(const bf16x8*)&As[(wave * 32 + mi * 16 + l15) * 40 + quad * 8];
#pragma unroll
        for (int ni = 0; ni < 4; ++ni)
            bf[ni] = *(const bf16x8*)&Bs[(ni * 16 + l15) * 40 + quad * 8];
#pragma unroll
        for (int mi = 0; mi < 2; ++mi)
#pragma unroll
            for (int ni = 0; ni < 4; ++ni)
                acc[mi][ni] = __builtin_amdgcn_mfma_f32_16x16x32_bf16(
                    af[mi], bf[ni], acc[mi][ni], 0, 0, 0);
    }

    if (MODE == 2) {
        // ---- V^T epilogue: stage 128(s) x 64(v) accs into LDS as [v][s],
        // then coalesced store to Cv[v][s] with row stride S_LEN.
        __syncthreads();                  // last K-step's LDS reads done
#pragma unroll
        for (int mi = 0; mi < 2; ++mi)
#pragma unroll
            for (int ni = 0; ni < 4; ++ni) {
                const float bv = bias[col0 + ni * 16 + l15];
                const int lrow = wave * 32 + mi * 16 + quad * 4;   // mult of 4
                uint2 uu;
                uu.x = pack_bf16x2((acc[mi][ni][0] + bv) * scale,
                                   (acc[mi][ni][1] + bv) * scale);
                uu.y = pack_bf16x2((acc[mi][ni][2] + bv) * scale,
                                   (acc[mi][ni][3] + bv) * scale);
                *(uint2*)&Ts[(ni * 16 + l15) * 136 + lrow] = uu;
            }
        __syncthreads();
        const int v = tid >> 2, s0 = (tid & 3) * 32;
#pragma unroll
        for (int i = 0; i < 4; ++i) {
            const uint4 d = *(const uint4*)&Ts[v * 136 + s0 + 8 * i];
            *(uint4*)&((ushort*)Cv)[(size_t)(col0 + v) * S_LEN + row0 + s0 + 8 * i] = d;
        }
        return;
    }

#pragma unroll
    for (int mi = 0; mi < 2; ++mi)
#pragma unroll
        for (int ni = 0; ni < 4; ++ni) {
            const int col = col0 + ni * 16 + l15;
            const float bv = bias[col];
#pragma unroll
            for (int reg = 0; reg < 4; ++reg) {
                const int row = row0 + wave * 32 + mi * 16 + quad * 4 + reg;
                const float val = (acc[mi][ni][reg] + bv) * scale;
                if (MODE == 1)
                    ((float*)Cv)[(size_t)row * N + col] = val;
                else
                    ((ushort*)Cv)[(size_t)row * N + col] = f32_to_bf16(val);
            }
        }
}

// XCD-aware 2D-chunk decode for 512-block GEMMs (32 col-tiles x 16 row-tiles).
// Dispatch round-robins blocks over 8 XCDs (xcd = d & 7); give each XCD an
// 8x8 tile rect so it touches 8 A-panels (4 MB) + 8 B-panels (2 MB) ~ L2-sized.
__device__ __forceinline__ void xcd_decode_32x16(int d, int& bx, int& by) {
    const int xcd = d & 7, i = d >> 3;          // i in [0,64)
    bx = (xcd & 3) * 8 + (i & 7);
    by = (xcd >> 2) * 8 + (i >> 3);
}

// Q projection: [2048,2048]x[2048,2048], bf16 out, scale folded
__global__ __launch_bounds__(256) void gemm_q(
        const ushort* __restrict__ A, const ushort* __restrict__ Bt,
        const float* __restrict__ bias, ushort* __restrict__ Cv, int K,
        float scale) {
    __shared__ ushort smem[128 * 40 + 64 * 40];
    int bx, by; xcd_decode_32x16(blockIdx.x, bx, by);
    gemm_body_128x64<0>(A, Bt, bias, Cv, smem, smem + 128 * 40, nullptr,
                        2048, K, scale, bx, by);
}

// O projection: f32 out
__global__ __launch_bounds__(256) void gemm_o(
        const ushort* __restrict__ A, const ushort* __restrict__ Bt,
        const float* __restrict__ bias, float* __restrict__ Cv, int K) {
    __shared__ ushort smem[128 * 40 + 64 * 40];
    int bx, by; xcd_decode_32x16(blockIdx.x, bx, by);
    gemm_body_128x64<1>(A, Bt, bias, Cv, smem, smem + 128 * 40, nullptr,
                        2048, K, 1.0f, bx, by);
}

// K and V projections fused via gridDim.z; V writes V^T directly (MODE 2).
__global__ __launch_bounds__(256) void gemm_kv(
        const ushort* __restrict__ Xk, const ushort* __restrict__ Xv,
        const ushort* __restrict__ Wkt, const ushort* __restrict__ Wvt,
        const float* __restrict__ bk, const float* __restrict__ bv,
        ushort* __restrict__ Kb, ushort* __restrict__ Vtp, int K) {
    __shared__ ushort smem[64 * 136];   // 8704 >= 128*40 + 64*40 = 7680
    ushort* As = smem;
    ushort* Bs = smem + 128 * 40;
    if (blockIdx.z == 0)
        gemm_body_128x64<0>(Xk, Wkt, bk, Kb, As, Bs, nullptr, 512, K, 1.0f,
                            blockIdx.x, blockIdx.y);
    else
        gemm_body_128x64<2>(Xv, Wvt, bv, Vtp, As, Bs, smem, 512, K, 1.0f,
                            blockIdx.x, blockIdx.y);
}

// ------------------------------------------------------ MFMA flash attention
// Grid (32, 16, 2): x = head, y = pair index, z = sel; block handles ONE
// 64-row q-tile: qt = z ? 31-y : y.  1024 blocks, 4 blocks/CU all-resident
// (2x the old occupancy).  Ordering (head fastest) makes every stride-256
// dispatch class carry (y+1)+(y+9)+(32-y)+(24-y) = 66 j-tile-units — per-CU
// causal load stays balanced with blocks pinned round-robin to CUs.  Also:
// each XCD sees only 4 of 8 KV groups -> 2 MB KV footprint per 4 MB L2.
// 4 waves/block; wave owns a 16-row Q stripe.
//
// SWAPPED-OPERAND version: S^T = mfma(K_frag, Q_frag) puts q in the C-layout
// column (l15) — each lane owns ONE q row. Online-softmax state (m, l) is a
// single scalar per lane; row max/sum = 15 in-lane ops + 2 shfl_xor (16, 32).
// P^T packs into per-wave LDS as [q][key] (8B vector stores) and reads back
// contiguously as the PV B-frag. PV computes O^T = mfma(V^T_frag, P^T_frag);
// V^T LDS tile is already in A-frag layout. Scale (1/sqrt(dk) * log2e) is
// pre-folded into Q; exp = exp2. Defer-max rescale (T13).
__global__ __launch_bounds__(256) void gqa_attn_mfma(
        const ushort* __restrict__ Qb, const ushort* __restrict__ Kb,
        const ushort* __restrict__ Vt, ushort* __restrict__ Ab) {
    __shared__ ushort Ks[64 * 72];       // [key][d]
    __shared__ ushort Vs[64 * 72];       // [d][key]
    __shared__ ushort Ps[4][16 * 72];    // per-wave P^T as [q][key]

    const int h    = blockIdx.x, g = h >> 2;
    const int tid  = threadIdx.x;
    const int lane = tid & 63, wave = tid >> 6;
    const int l15  = lane & 15, quad = lane >> 4;
    const int NT   = S_LEN / 64;         // 32 q-tiles
    const float DEFER_THR = 11.5416f;    // 8 * log2(e)

    // per-thread staging coordinates (fixed across tiles)
    const int srow = tid >> 2, sch = tid & 3;
    const ushort* kbase = Kb + (size_t)srow * (NG * DK) + g * DK + sch * 16;
    const ushort* vbase = Vt + (size_t)(g * 64 + srow) * S_LEN + sch * 16;

    const int qt = blockIdx.z ? (NT - 1 - (int)blockIdx.y) : (int)blockIdx.y;
    const int qr = qt * 64 + wave * 16;          // wave's first q row

    // Q frags (scale pre-folded at projection time), d=0..31 / 32..63
    bf16x8 qa0, qa1;
    {
        const size_t base = (size_t)(qr + l15) * (NH * DK) + (size_t)h * DK + quad * 8;
        qa0 = *(const bf16x8*)&Qb[base];
        qa1 = *(const bf16x8*)&Qb[base + 32];
    }

    f32x4 o[4];                          // O^T: lane = q (l15); rows = d
#pragma unroll
    for (int dt = 0; dt < 4; ++dt) { f32x4 z = {0.f,0.f,0.f,0.f}; o[dt] = z; }
    float m = -1e30f;                    // per-lane (per-q) running max, log2 domain
    float l = 0.f;                       // per-lane running sum

    // preload tile 0
    bf16x8 kr0 = *(const bf16x8*)(kbase);
    bf16x8 kr1 = *(const bf16x8*)(kbase + 8);
    bf16x8 vr0 = *(const bf16x8*)(vbase);
    bf16x8 vr1 = *(const bf16x8*)(vbase + 8);

    for (int jt = 0; jt <= qt; ++jt) {
        __syncthreads();                 // prior LDS reads complete
        *(bf16x8*)&Ks[srow * 72 + sch * 16]     = kr0;
        *(bf16x8*)&Ks[srow * 72 + sch * 16 + 8] = kr1;
        *(bf16x8*)&Vs[srow * 72 + sch * 16]     = vr0;
        *(bf16x8*)&Vs[srow * 72 + sch * 16 + 8] = vr1;
        __syncthreads();

        // prefetch tile jt+1 (flies during compute below)
        if (jt < qt) {
            const size_t ko = (size_t)(jt + 1) * 64 * (NG * DK);
            const size_t vo = (size_t)(jt + 1) * 64;
            kr0 = *(const bf16x8*)(kbase + ko);
            kr1 = *(const bf16x8*)(kbase + ko + 8);
            vr0 = *(const bf16x8*)(vbase + vo);
            vr1 = *(const bf16x8*)(vbase + vo + 8);
        }

        // S^T = K Q^T : C-layout col = q (l15), row = key (quad*4+r, +16*kt)
        f32x4 s[4];
#pragma unroll
        for (int kt = 0; kt < 4; ++kt) {
            const bf16x8 kb0 = *(const bf16x8*)&Ks[(kt * 16 + l15) * 72 + quad * 8];
            const bf16x8 kb1 = *(const bf16x8*)&Ks[(kt * 16 + l15) * 72 + 32 + quad * 8];
            f32x4 acc = {0.f, 0.f, 0.f, 0.f};
            acc = __builtin_amdgcn_mfma_f32_16x16x32_bf16(kb0, qa0, acc, 0, 0, 0);
            acc = __builtin_amdgcn_mfma_f32_16x16x32_bf16(kb1, qa1, acc, 0, 0, 0);
            s[kt] = acc;
        }

        // causal mask (diagonal tile only; scale already folded into Q)
        if (jt == qt) {
            const int row = wave * 16 + l15;   // q within the 64-row tile
#pragma unroll
            for (int kt = 0; kt < 4; ++kt)
#pragma unroll
                for (int r = 0; r < 4; ++r) {
                    const int key = kt * 16 + quad * 4 + r;
                    if (key > row) s[kt][r] = -1e30f;
                }
        }

        // tile max for this q row: 15 in-lane + cross-quad (xor 16, 32)
        float pmax;
        {
            const float t0 = fmaxf(fmaxf(s[0][0], s[0][1]), fmaxf(s[0][2], s[0][3]));
            const float t1 = fmaxf(fmaxf(s[1][0], s[1][1]), fmaxf(s[1][2], s[1][3]));
            const float t2 = fmaxf(fmaxf(s[2][0], s[2][1]), fmaxf(s[2][2], s[2][3]));
            const float t3 = fmaxf(fmaxf(s[3][0], s[3][1]), fmaxf(s[3][2], s[3][3]));
            pmax = fmaxf(fmaxf(t0, t1), fmaxf(t2, t3));
        }
        pmax = fmaxf(pmax, __shfl_xor(pmax, 16, 64));
        pmax = fmaxf(pmax, __shfl_xor(pmax, 32, 64));

        // defer-max: only rescale when the tile max grew past threshold
        if (!__all(pmax - m <= DEFER_THR)) {
            const float mnew  = fmaxf(m, pmax);
            const float alpha = __builtin_amdgcn_exp2f(m - mnew);
            l *= alpha;
#pragma unroll
            for (int dt = 0; dt < 4; ++dt)
#pragma unroll
                for (int r = 0; r < 4; ++r) o[dt][r] *= alpha;
            m = mnew;
        }

        float p[4][4];
#pragma unroll
        for (int kt = 0; kt < 4; ++kt)
#pragma unroll
            for (int r = 0; r < 4; ++r)
                p[kt][r] = __builtin_amdgcn_exp2f(s[kt][r] - m);

        float rsum;
        {
            const float u0 = (p[0][0] + p[0][1]) + (p[0][2] + p[0][3]);
            const float u1 = (p[1][0] + p[1][1]) + (p[1][2] + p[1][3]);
            const float u2 = (p[2][0] + p[2][1]) + (p[2][2] + p[2][3]);
            const float u3 = (p[3][0] + p[3][1]) + (p[3][2] + p[3][3]);
            rsum = (u0 + u1) + (u2 + u3);
        }
        rsum += __shfl_xor(rsum, 16, 64);
        rsum += __shfl_xor(rsum, 32, 64);
        l += rsum;

        // P^T -> per-wave LDS [q][key]: 8B vector stores, contiguous keys
        ushort* Pw = &Ps[wave][0];
#pragma unroll
        for (int kt = 0; kt < 4; ++kt) {
            uint2 uu;
            uu.x = pack_bf16x2(p[kt][0], p[kt][1]);
            uu.y = pack_bf16x2(p[kt][2], p[kt][3]);
            *(uint2*)&Pw[l15 * 72 + kt * 16 + quad * 4] = uu;
        }
        const bf16x8 pa0 = *(const bf16x8*)&Pw[l15 * 72 + quad * 8];
        const bf16x8 pa1 = *(const bf16x8*)&Pw[l15 * 72 + 32 + quad * 8];

        // O^T += V^T P^T : A = V^T tile (already [d][key] in LDS), B = P^T
#pragma unroll
        for (int dt = 0; dt < 4; ++dt) {
            const bf16x8 vb0 = *(const bf16x8*)&Vs[(dt * 16 + l15) * 72 + quad * 8];
            const bf16x8 vb1 = *(const bf16x8*)&Vs[(dt * 16 + l15) * 72 + 32 + quad * 8];
            o[dt] = __builtin_amdgcn_mfma_f32_16x16x32_bf16(vb0, pa0, o[dt], 0, 0, 0);
            o[dt] = __builtin_amdgcn_mfma_f32_16x16x32_bf16(vb1, pa1, o[dt], 0, 0, 0);
        }
    }

    // epilogue: lane holds O^T[d = dt*16 + quad*4 + r][q = l15]
    const float invl = 1.0f / l;
#pragma unroll
    for (int dt = 0; dt < 4; ++dt) {
        uint2 uu;
        uu.x = pack_bf16x2(o[dt][0] * invl, o[dt][1] * invl);
        uu.y = pack_bf16x2(o[dt][2] * invl, o[dt][3] * invl);
        *(uint2*)&Ab[(size_t)(qr + l15) * (NH * DV) + (size_t)h * DV + dt * 16 + quad * 4] = uu;
    }
}

// ---------------------------------------------------------------------------
extern "C" void kernel_launch(void* const* d_in, const int* in_sizes, int n_in,
                              void* d_out, int out_size, void* d_ws, size_t ws_size,
                              hipStream_t stream) {
    const float* queries = (const float*)d_in[0];
    const float* keys    = (const float*)d_in[1];
    const float* values  = (const float*)d_in[2];
    const float* Wq      = (const float*)d_in[3];
    const float* bq      = (const float*)d_in[4];
    const float* Wk      = (const float*)d_in[5];
    const float* bk      = (const float*)d_in[6];
    const float* Wv      = (const float*)d_in[7];
    const float* bv      = (const float*)d_in[8];
    const float* Wo      = (const float*)d_in[9];
    const float* bo      = (const float*)d_in[10];
    float* out = (float*)d_out;

    const size_t MB = 1024 * 1024;
    unsigned char* w = (unsigned char*)d_ws;
    ushort* Xq  = (ushort*)(w + 0 * MB);    // [2048][2048] bf16
    ushort* Xk  = (ushort*)(w + 8 * MB);
    ushort* Xv  = (ushort*)(w + 16 * MB);
    ushort* Wqt = (ushort*)(w + 24 * MB);   // [2048][2048]
    ushort* Wkt = (ushort*)(w + 32 * MB);   // [512][2048]
    ushort* Wvt = (ushort*)(w + 34 * MB);
    ushort* Wot = (ushort*)(w + 36 * MB);   // [2048][2048]
    ushort* Qb  = (ushort*)(w + 44 * MB);   // [2048][2048]
    ushort* Kb  = (ushort*)(w + 52 * MB);   // [2048][512]
    ushort* Vtp = (ushort*)(w + 54 * MB);   // V^T [512][2048] (written directly)
    ushort* Ab  = (ushort*)(w + 56 * MB);   // [2048][2048]

    const int n8 = (S_LEN * DMODEL) / 8;
    cast3_f32_to_bf16<<<dim3(1024, 1, 3), 256, 0, stream>>>(
        queries, keys, values, Xq, Xk, Xv, n8);

    dim3 tb(32, 8);
    transpose_cast4<<<dim3(160, 64), tb, 0, stream>>>(
        Wq, Wk, Wv, Wo, Wqt, Wkt, Wvt, Wot);

    // Q projection (XCD-swizzled); softmax scale * log2(e) folded into Q
    const float QSCALE = 0.125f * 1.44269504f;
    gemm_q<<<512, 256, 0, stream>>>(Xq, Wqt, bq, Qb, DMODEL, QSCALE);

    // K and V projections fused (z=0: K, z=1: V -> V^T direct)
    gemm_kv<<<dim3(8, 16, 2), 256, 0, stream>>>(
        Xk, Xv, Wkt, Wvt, bk, bv, Kb, Vtp, DMODEL);

    // attention: 1024 blocks, one q-tile each, stride-256-balanced ordering
    gqa_attn_mfma<<<dim3(32, 16, 2), 256, 0, stream>>>(Qb, Kb, Vtp, Ab);

    // O projection (XCD-swizzled): [2048,2048] @ [2048,2048] -> f32 out
    gemm_o<<<512, 256, 0, stream>>>(Ab, Wot, bo, out, DMODEL);
}

// Round 7
// 272.159 us; speedup vs baseline: 1.1747x; 1.0543x over previous
//
#include <hip/hip_runtime.h>
#include <hip/hip_bf16.h>

#define S_LEN  2048
#define DMODEL 2048
#define NH     32
#define NG     8
#define DK     64
#define DV     64

typedef short bf16x8 __attribute__((ext_vector_type(8)));
typedef float f32x4  __attribute__((ext_vector_type(4)));

__device__ __forceinline__ ushort f32_to_bf16(float f) {
    uint u = __float_as_uint(f);
    return (ushort)((u + 0x7fffu + ((u >> 16) & 1u)) >> 16);   // RNE
}
__device__ __forceinline__ float bf16_to_f32(ushort h) {
    return __uint_as_float(((uint)h) << 16);
}
__device__ __forceinline__ uint pack_bf16x2(float a, float b) {
    return (uint)f32_to_bf16(a) | ((uint)f32_to_bf16(b) << 16);
}

// ------------------------------------------- fused cast f32->bf16 (q,k,v in one)
__global__ void cast3_f32_to_bf16(const float* __restrict__ q,
                                  const float* __restrict__ k,
                                  const float* __restrict__ v,
                                  ushort* __restrict__ xq,
                                  ushort* __restrict__ xk,
                                  ushort* __restrict__ xv, int n8) {
    const float* in  = blockIdx.z == 0 ? q  : (blockIdx.z == 1 ? k  : v);
    ushort*      out = blockIdx.z == 0 ? xq : (blockIdx.z == 1 ? xk : xv);
    int i = blockIdx.x * blockDim.x + threadIdx.x;
    const int stride = gridDim.x * blockDim.x;
    for (; i < n8; i += stride) {
        const float4 a = ((const float4*)in)[2 * i];
        const float4 b = ((const float4*)in)[2 * i + 1];
        uint4 o;
        o.x = (uint)f32_to_bf16(a.x) | ((uint)f32_to_bf16(a.y) << 16);
        o.y = (uint)f32_to_bf16(a.z) | ((uint)f32_to_bf16(a.w) << 16);
        o.z = (uint)f32_to_bf16(b.x) | ((uint)f32_to_bf16(b.y) << 16);
        o.w = (uint)f32_to_bf16(b.z) | ((uint)f32_to_bf16(b.w) << 16);
        ((uint4*)out)[i] = o;
    }
}

// ---------------------- fused W[K][N] f32 -> Wt[N][K] bf16 for all four weights
// grid.x block ranges: [0,64) Wq, [64,80) Wk, [80,96) Wv, [96,160) Wo. K=2048.
__global__ void transpose_cast4(const float* __restrict__ Wq,
                                const float* __restrict__ Wk,
                                const float* __restrict__ Wv,
                                const float* __restrict__ Wo,
                                ushort* __restrict__ Wqt, ushort* __restrict__ Wkt,
                                ushort* __restrict__ Wvt, ushort* __restrict__ Wot) {
    __shared__ float t[32][33];
    int bx = blockIdx.x;
    const float* W; ushort* Wt; int N;
    if (bx < 64)      { W = Wq; Wt = Wqt; N = 2048; }
    else if (bx < 80) { W = Wk; Wt = Wkt; N = 512;  bx -= 64; }
    else if (bx < 96) { W = Wv; Wt = Wvt; N = 512;  bx -= 80; }
    else              { W = Wo; Wt = Wot; N = 2048; bx -= 96; }
    const int n0 = bx * 32, k0 = blockIdx.y * 32;
    const int tx = threadIdx.x, ty = threadIdx.y;   // 32 x 8
#pragma unroll
    for (int i = 0; i < 4; ++i)
        t[ty + 8 * i][tx] = W[(size_t)(k0 + ty + 8 * i) * N + n0 + tx];
    __syncthreads();
#pragma unroll
    for (int i = 0; i < 4; ++i)
        Wt[(size_t)(n0 + ty + 8 * i) * 2048 + k0 + tx] = f32_to_bf16(t[tx][ty + 8 * i]);
}

// ------------------------------------------------------------- bf16 MFMA GEMM
// C[M][N] = (A[M][K] @ Bt[N][K]^T + bias) * scale.  128(M)x64(N) tile, 4 waves
// stacked in M (each: 32 rows x 64 cols = 2x4 frags of mfma_f32_16x16x32_bf16).
// BK=64: halves barrier count vs BK=32 and doubles the compute window
// (32 MFMA + 12 ds_read_b128) covering each register-prefetch's load->ds_write
// latency.  LDS row stride 72 shorts (144B -> 2-way bank alias only, free).
// MODE: 0 = bf16 C, 1 = f32 C, 2 = bf16 C^T (V^T, output stride S_LEN) via LDS.
template <int MODE>
__device__ __forceinline__ void gemm_body_128x64(
        const ushort* __restrict__ A, const ushort* __restrict__ Bt,
        const float* __restrict__ bias, void* __restrict__ Cv,
        ushort* As, ushort* Bs, ushort* Ts, int N, int K, float scale,
        int bx, int by) {
    const int tid  = threadIdx.x;
    const int lane = tid & 63, wave = tid >> 6;
    const int l15 = lane & 15, quad = lane >> 4;
    const int row0 = by * 128, col0 = bx * 64;

    f32x4 acc[2][4];
#pragma unroll
    for (int i = 0; i < 2; ++i)
#pragma unroll
        for (int j = 0; j < 4; ++j) { f32x4 z = {0.f,0.f,0.f,0.f}; acc[i][j] = z; }

    // staging coords (BK=64): A 128x64 (4 b128/thread), B 64x64 (2 b128/thread)
    const int ar = tid >> 1, ak = (tid & 1) * 32;
    const int br = tid >> 2, bk = (tid & 3) * 16;
    const ushort* aptr = A  + (size_t)(row0 + ar) * K + ak;
    const ushort* bptr = Bt + (size_t)(col0 + br) * K + bk;

    bf16x8 a0 = *(const bf16x8*)(aptr);
    bf16x8 a1 = *(const bf16x8*)(aptr + 8);
    bf16x8 a2 = *(const bf16x8*)(aptr + 16);
    bf16x8 a3 = *(const bf16x8*)(aptr + 24);
    bf16x8 b0 = *(const bf16x8*)(bptr);
    bf16x8 b1 = *(const bf16x8*)(bptr + 8);

    for (int k0 = 0; k0 < K; k0 += 64) {
        __syncthreads();
        *(bf16x8*)&As[ar * 72 + ak]      = a0;
        *(bf16x8*)&As[ar * 72 + ak + 8]  = a1;
        *(bf16x8*)&As[ar * 72 + ak + 16] = a2;
        *(bf16x8*)&As[ar * 72 + ak + 24] = a3;
        *(bf16x8*)&Bs[br * 72 + bk]      = b0;
        *(bf16x8*)&Bs[br * 72 + bk + 8]  = b1;
        __syncthreads();

        if (k0 + 64 < K) {
            a0 = *(const bf16x8*)(aptr + k0 + 64);
            a1 = *(const bf16x8*)(aptr + k0 + 72);
            a2 = *(const bf16x8*)(aptr + k0 + 80);
            a3 = *(const bf16x8*)(aptr + k0 + 88);
            b0 = *(const bf16x8*)(bptr + k0 + 64);
            b1 = *(const bf16x8*)(bptr + k0 + 72);
        }

#pragma unroll
        for (int kk = 0; kk < 2; ++kk) {
            bf16x8 af[2], bf[4];
#pragma unroll
            for (int mi = 0; mi < 2; ++mi)
                af[mi] = *(const bf16x8*)&As[(wave * 32 + mi * 16 + l15) * 72 + kk * 32 + quad * 8];
#pragma unroll
            for (int ni = 0; ni < 4; ++ni)
                bf[ni] = *(const bf16x8*)&Bs[(ni * 16 + l15) * 72 + kk * 32 + quad * 8];
#pragma unroll
            for (int mi = 0; mi < 2; ++mi)
#pragma unroll
                for (int ni = 0; ni < 4; ++ni)
                    acc[mi][ni] = __builtin_amdgcn_mfma_f32_16x16x32_bf16(
                        af[mi], bf[ni], acc[mi][ni], 0, 0, 0);
        }
    }

    if (MODE == 2) {
        // ---- V^T epilogue: stage 128(s) x 64(v) accs into LDS as [v][s],
        // then coalesced store to Cv[v][s] with row stride S_LEN.
        __syncthreads();                  // last K-step's LDS reads done
#pragma unroll
        for (int mi = 0; mi < 2; ++mi)
#pragma unroll
            for (int ni = 0; ni < 4; ++ni) {
                const float bv = bias[col0 + ni * 16 + l15];
                const int lrow = wave * 32 + mi * 16 + quad * 4;   // mult of 4
                uint2 uu;
                uu.x = pack_bf16x2((acc[mi][ni][0] + bv) * scale,
                                   (acc[mi][ni][1] + bv) * scale);
                uu.y = pack_bf16x2((acc[mi][ni][2] + bv) * scale,
                                   (acc[mi][ni][3] + bv) * scale);
                *(uint2*)&Ts[(ni * 16 + l15) * 136 + lrow] = uu;
            }
        __syncthreads();
        const int v = tid >> 2, s0 = (tid & 3) * 32;
#pragma unroll
        for (int i = 0; i < 4; ++i) {
            const uint4 d = *(const uint4*)&Ts[v * 136 + s0 + 8 * i];
            *(uint4*)&((ushort*)Cv)[(size_t)(col0 + v) * S_LEN + row0 + s0 + 8 * i] = d;
        }
        return;
    }

#pragma unroll
    for (int mi = 0; mi < 2; ++mi)
#pragma unroll
        for (int ni = 0; ni < 4; ++ni) {
            const int col = col0 + ni * 16 + l15;
            const float bv = bias[col];
#pragma unroll
            for (int reg = 0; reg < 4; ++reg) {
                const int row = row0 + wave * 32 + mi * 16 + quad * 4 + reg;
                const float val = (acc[mi][ni][reg] + bv) * scale;
                if (MODE == 1)
                    ((float*)Cv)[(size_t)row * N + col] = val;
                else
                    ((ushort*)Cv)[(size_t)row * N + col] = f32_to_bf16(val);
            }
        }
}

// XCD-aware 2D-chunk decode for 512-block GEMMs (32 col-tiles x 16 row-tiles).
// Dispatch round-robins blocks over 8 XCDs (xcd = d & 7); give each XCD an
// 8x8 tile rect so it touches 8 A-panels (4 MB) + 8 B-panels (2 MB) ~ L2-sized.
__device__ __forceinline__ void xcd_decode_32x16(int d, int& bx, int& by) {
    const int xcd = d & 7, i = d >> 3;          // i in [0,64)
    bx = (xcd & 3) * 8 + (i & 7);
    by = (xcd >> 2) * 8 + (i >> 3);
}

// Q projection: [2048,2048]x[2048,2048], bf16 out, scale folded
__global__ __launch_bounds__(256) void gemm_q(
        const ushort* __restrict__ A, const ushort* __restrict__ Bt,
        const float* __restrict__ bias, ushort* __restrict__ Cv, int K,
        float scale) {
    __shared__ ushort smem[128 * 72 + 64 * 72];
    int bx, by; xcd_decode_32x16(blockIdx.x, bx, by);
    gemm_body_128x64<0>(A, Bt, bias, Cv, smem, smem + 128 * 72, nullptr,
                        2048, K, scale, bx, by);
}

// O projection: f32 out
__global__ __launch_bounds__(256) void gemm_o(
        const ushort* __restrict__ A, const ushort* __restrict__ Bt,
        const float* __restrict__ bias, float* __restrict__ Cv, int K) {
    __shared__ ushort smem[128 * 72 + 64 * 72];
    int bx, by; xcd_decode_32x16(blockIdx.x, bx, by);
    gemm_body_128x64<1>(A, Bt, bias, Cv, smem, smem + 128 * 72, nullptr,
                        2048, K, 1.0f, bx, by);
}

// K and V projections fused via gridDim.z; V writes V^T directly (MODE 2).
__global__ __launch_bounds__(256) void gemm_kv(
        const ushort* __restrict__ Xk, const ushort* __restrict__ Xv,
        const ushort* __restrict__ Wkt, const ushort* __restrict__ Wvt,
        const float* __restrict__ bk, const float* __restrict__ bv,
        ushort* __restrict__ Kb, ushort* __restrict__ Vtp, int K) {
    __shared__ ushort smem[128 * 72 + 64 * 72];   // 13824 shorts; Ts needs 8704
    ushort* As = smem;
    ushort* Bs = smem + 128 * 72;
    if (blockIdx.z == 0)
        gemm_body_128x64<0>(Xk, Wkt, bk, Kb, As, Bs, nullptr, 512, K, 1.0f,
                            blockIdx.x, blockIdx.y);
    else
        gemm_body_128x64<2>(Xv, Wvt, bv, Vtp, As, Bs, smem, 512, K, 1.0f,
                            blockIdx.x, blockIdx.y);
}

// ------------------------------------------------------ MFMA flash attention
// Grid (32, 16, 2): x = head, y = pair index, z = sel; block handles ONE
// 64-row q-tile: qt = z ? 31-y : y.  1024 blocks, 4 blocks/CU all-resident.
// Ordering (head fastest) keeps per-CU causal load balanced (66 j-tile-units
// per stride-256 class) and gives each XCD a 4-of-8 KV-group L2 footprint.
// 4 waves/block; wave owns a 16-row Q stripe.
//
// SWAPPED-OPERAND version: S^T = mfma(K_frag, Q_frag) puts q in the C-layout
// column (l15) — each lane owns ONE q row. Online-softmax state (m, l) is a
// single scalar per lane; row max/sum = 15 in-lane ops + 2 shfl_xor (16, 32).
// P^T packs into per-wave LDS as [q][key] (8B vector stores) and reads back
// contiguously as the PV B-frag. PV computes O^T = mfma(V^T_frag, P^T_frag);
// V^T LDS tile is already in A-frag layout. Scale (1/sqrt(dk) * log2e) is
// pre-folded into Q; exp = exp2. Defer-max rescale (T13).
__global__ __launch_bounds__(256) void gqa_attn_mfma(
        const ushort* __restrict__ Qb, const ushort* __restrict__ Kb,
        const ushort* __restrict__ Vt, ushort* __restrict__ Ab) {
    __shared__ ushort Ks[64 * 72];       // [key][d]
    __shared__ ushort Vs[64 * 72];       // [d][key]
    __shared__ ushort Ps[4][16 * 72];    // per-wave P^T as [q][key]

    const int h    = blockIdx.x, g = h >> 2;
    const int tid  = threadIdx.x;
    const int lane = tid & 63, wave = tid >> 6;
    const int l15  = lane & 15, quad = lane >> 4;
    const int NT   = S_LEN / 64;         // 32 q-tiles
    const float DEFER_THR = 11.5416f;    // 8 * log2(e)

    // per-thread staging coordinates (fixed across tiles)
    const int srow = tid >> 2, sch = tid & 3;
    const ushort* kbase = Kb + (size_t)srow * (NG * DK) + g * DK + sch * 16;
    const ushort* vbase = Vt + (size_t)(g * 64 + srow) * S_LEN + sch * 16;

    const int qt = blockIdx.z ? (NT - 1 - (int)blockIdx.y) : (int)blockIdx.y;
    const int qr = qt * 64 + wave * 16;          // wave's first q row

    // Q frags (scale pre-folded at projection time), d=0..31 / 32..63
    bf16x8 qa0, qa1;
    {
        const size_t base = (size_t)(qr + l15) * (NH * DK) + (size_t)h * DK + quad * 8;
        qa0 = *(const bf16x8*)&Qb[base];
        qa1 = *(const bf16x8*)&Qb[base + 32];
    }

    f32x4 o[4];                          // O^T: lane = q (l15); rows = d
#pragma unroll
    for (int dt = 0; dt < 4; ++dt) { f32x4 z = {0.f,0.f,0.f,0.f}; o[dt] = z; }
    float m = -1e30f;                    // per-lane (per-q) running max, log2 domain
    float l = 0.f;                       // per-lane running sum

    // preload tile 0
    bf16x8 kr0 = *(const bf16x8*)(kbase);
    bf16x8 kr1 = *(const bf16x8*)(kbase + 8);
    bf16x8 vr0 = *(const bf16x8*)(vbase);
    bf16x8 vr1 = *(const bf16x8*)(vbase + 8);

    for (int jt = 0; jt <= qt; ++jt) {
        __syncthreads();                 // prior LDS reads complete
        *(bf16x8*)&Ks[srow * 72 + sch * 16]     = kr0;
        *(bf16x8*)&Ks[srow * 72 + sch * 16 + 8] = kr1;
        *(bf16x8*)&Vs[srow * 72 + sch * 16]     = vr0;
        *(bf16x8*)&Vs[srow * 72 + sch * 16 + 8] = vr1;
        __syncthreads();

        // prefetch tile jt+1 (flies during compute below)
        if (jt < qt) {
            const size_t ko = (size_t)(jt + 1) * 64 * (NG * DK);
            const size_t vo = (size_t)(jt + 1) * 64;
            kr0 = *(const bf16x8*)(kbase + ko);
            kr1 = *(const bf16x8*)(kbase + ko + 8);
            vr0 = *(const bf16x8*)(vbase + vo);
            vr1 = *(const bf16x8*)(vbase + vo + 8);
        }

        // S^T = K Q^T : C-layout col = q (l15), row = key (quad*4+r, +16*kt)
        f32x4 s[4];
#pragma unroll
        for (int kt = 0; kt < 4; ++kt) {
            const bf16x8 kb0 = *(const bf16x8*)&Ks[(kt * 16 + l15) * 72 + quad * 8];
            const bf16x8 kb1 = *(const bf16x8*)&Ks[(kt * 16 + l15) * 72 + 32 + quad * 8];
            f32x4 acc = {0.f, 0.f, 0.f, 0.f};
            acc = __builtin_amdgcn_mfma_f32_16x16x32_bf16(kb0, qa0, acc, 0, 0, 0);
            acc = __builtin_amdgcn_mfma_f32_16x16x32_bf16(kb1, qa1, acc, 0, 0, 0);
            s[kt] = acc;
        }

        // causal mask (diagonal tile only; scale already folded into Q)
        if (jt == qt) {
            const int row = wave * 16 + l15;   // q within the 64-row tile
#pragma unroll
            for (int kt = 0; kt < 4; ++kt)
#pragma unroll
                for (int r = 0; r < 4; ++r) {
                    const int key = kt * 16 + quad * 4 + r;
                    if (key > row) s[kt][r] = -1e30f;
                }
        }

        // tile max for this q row: 15 in-lane + cross-quad (xor 16, 32)
        float pmax;
        {
            const float t0 = fmaxf(fmaxf(s[0][0], s[0][1]), fmaxf(s[0][2], s[0][3]));
            const float t1 = fmaxf(fmaxf(s[1][0], s[1][1]), fmaxf(s[1][2], s[1][3]));
            const float t2 = fmaxf(fmaxf(s[2][0], s[2][1]), fmaxf(s[2][2], s[2][3]));
            const float t3 = fmaxf(fmaxf(s[3][0], s[3][1]), fmaxf(s[3][2], s[3][3]));
            pmax = fmaxf(fmaxf(t0, t1), fmaxf(t2, t3));
        }
        pmax = fmaxf(pmax, __shfl_xor(pmax, 16, 64));
        pmax = fmaxf(pmax, __shfl_xor(pmax, 32, 64));

        // defer-max: only rescale when the tile max grew past threshold
        if (!__all(pmax - m <= DEFER_THR)) {
            const float mnew  = fmaxf(m, pmax);
            const float alpha = __builtin_amdgcn_exp2f(m - mnew);
            l *= alpha;
#pragma unroll
            for (int dt = 0; dt < 4; ++dt)
#pragma unroll
                for (int r = 0; r < 4; ++r) o[dt][r] *= alpha;
            m = mnew;
        }

        float p[4][4];
#pragma unroll
        for (int kt = 0; kt < 4; ++kt)
#pragma unroll
            for (int r = 0; r < 4; ++r)
                p[kt][r] = __builtin_amdgcn_exp2f(s[kt][r] - m);

        float rsum;
        {
            const float u0 = (p[0][0] + p[0][1]) + (p[0][2] + p[0][3]);
            const float u1 = (p[1][0] + p[1][1]) + (p[1][2] + p[1][3]);
            const float u2 = (p[2][0] + p[2][1]) + (p[2][2] + p[2][3]);
            const float u3 = (p[3][0] + p[3][1]) + (p[3][2] + p[3][3]);
            rsum = (u0 + u1) + (u2 + u3);
        }
        rsum += __shfl_xor(rsum, 16, 64);
        rsum += __shfl_xor(rsum, 32, 64);
        l += rsum;

        // P^T -> per-wave LDS [q][key]: 8B vector stores, contiguous keys
        ushort* Pw = &Ps[wave][0];
#pragma unroll
        for (int kt = 0; kt < 4; ++kt) {
            uint2 uu;
            uu.x = pack_bf16x2(p[kt][0], p[kt][1]);
            uu.y = pack_bf16x2(p[kt][2], p[kt][3]);
            *(uint2*)&Pw[l15 * 72 + kt * 16 + quad * 4] = uu;
        }
        const bf16x8 pa0 = *(const bf16x8*)&Pw[l15 * 72 + quad * 8];
        const bf16x8 pa1 = *(const bf16x8*)&Pw[l15 * 72 + 32 + quad * 8];

        // O^T += V^T P^T : A = V^T tile (already [d][key] in LDS), B = P^T
#pragma unroll
        for (int dt = 0; dt < 4; ++dt) {
            const bf16x8 vb0 = *(const bf16x8*)&Vs[(dt * 16 + l15) * 72 + quad * 8];
            const bf16x8 vb1 = *(const bf16x8*)&Vs[(dt * 16 + l15) * 72 + 32 + quad * 8];
            o[dt] = __builtin_amdgcn_mfma_f32_16x16x32_bf16(vb0, pa0, o[dt], 0, 0, 0);
            o[dt] = __builtin_amdgcn_mfma_f32_16x16x32_bf16(vb1, pa1, o[dt], 0, 0, 0);
        }
    }

    // epilogue: lane holds O^T[d = dt*16 + quad*4 + r][q = l15]
    const float invl = 1.0f / l;
#pragma unroll
    for (int dt = 0; dt < 4; ++dt) {
        uint2 uu;
        uu.x = pack_bf16x2(o[dt][0] * invl, o[dt][1] * invl);
        uu.y = pack_bf16x2(o[dt][2] * invl, o[dt][3] * invl);
        *(uint2*)&Ab[(size_t)(qr + l15) * (NH * DV) + (size_t)h * DV + dt * 16 + quad * 4] = uu;
    }
}

// ---------------------------------------------------------------------------
extern "C" void kernel_launch(void* const* d_in, const int* in_sizes, int n_in,
                              void* d_out, int out_size, void* d_ws, size_t ws_size,
                              hipStream_t stream) {
    const float* queries = (const float*)d_in[0];
    const float* keys    = (const float*)d_in[1];
    const float* values  = (const float*)d_in[2];
    const float* Wq      = (const float*)d_in[3];
    const float* bq      = (const float*)d_in[4];
    const float* Wk      = (const float*)d_in[5];
    const float* bk      = (const float*)d_in[6];
    const float* Wv      = (const float*)d_in[7];
    const float* bv      = (const float*)d_in[8];
    const float* Wo      = (const float*)d_in[9];
    const float* bo      = (const float*)d_in[10];
    float* out = (float*)d_out;

    const size_t MB = 1024 * 1024;
    unsigned char* w = (unsigned char*)d_ws;
    ushort* Xq  = (ushort*)(w + 0 * MB);    // [2048][2048] bf16
    ushort* Xk  = (ushort*)(w + 8 * MB);
    ushort* Xv  = (ushort*)(w + 16 * MB);
    ushort* Wqt = (ushort*)(w + 24 * MB);   // [2048][2048]
    ushort* Wkt = (ushort*)(w + 32 * MB);   // [512][2048]
    ushort* Wvt = (ushort*)(w + 34 * MB);
    ushort* Wot = (ushort*)(w + 36 * MB);   // [2048][2048]
    ushort* Qb  = (ushort*)(w + 44 * MB);   // [2048][2048]
    ushort* Kb  = (ushort*)(w + 52 * MB);   // [2048][512]
    ushort* Vtp = (ushort*)(w + 54 * MB);   // V^T [512][2048] (written directly)
    ushort* Ab  = (ushort*)(w + 56 * MB);   // [2048][2048]

    const int n8 = (S_LEN * DMODEL) / 8;
    cast3_f32_to_bf16<<<dim3(1024, 1, 3), 256, 0, stream>>>(
        queries, keys, values, Xq, Xk, Xv, n8);

    dim3 tb(32, 8);
    transpose_cast4<<<dim3(160, 64), tb, 0, stream>>>(
        Wq, Wk, Wv, Wo, Wqt, Wkt, Wvt, Wot);

    // Q projection (XCD-swizzled); softmax scale * log2(e) folded into Q
    const float QSCALE = 0.125f * 1.44269504f;
    gemm_q<<<512, 256, 0, stream>>>(Xq, Wqt, bq, Qb, DMODEL, QSCALE);

    // K and V projections fused (z=0: K, z=1: V -> V^T direct)
    gemm_kv<<<dim3(8, 16, 2), 256, 0, stream>>>(
        Xk, Xv, Wkt, Wvt, bk, bv, Kb, Vtp, DMODEL);

    // attention: 1024 blocks, one q-tile each, stride-256-balanced ordering
    gqa_attn_mfma<<<dim3(32, 16, 2), 256, 0, stream>>>(Qb, Kb, Vtp, Ab);

    // O projection (XCD-swizzled): [2048,2048] @ [2048,2048] -> f32 out
    gemm_o<<<512, 256, 0, stream>>>(Ab, Wot, bo, out, DMODEL);
}

// Round 9
// 269.521 us; speedup vs baseline: 1.1862x; 1.0098x over previous
//
#include <hip/hip_runtime.h>
#include <hip/hip_bf16.h>

#define S_LEN  2048
#define DMODEL 2048
#define NH     32
#define NG     8
#define DK     64
#define DV     64

typedef short bf16x8 __attribute__((ext_vector_type(8)));
typedef float f32x4  __attribute__((ext_vector_type(4)));

__device__ __forceinline__ ushort f32_to_bf16(float f) {
    uint u = __float_as_uint(f);
    return (ushort)((u + 0x7fffu + ((u >> 16) & 1u)) >> 16);   // RNE
}
__device__ __forceinline__ float bf16_to_f32(ushort h) {
    return __uint_as_float(((uint)h) << 16);
}
__device__ __forceinline__ uint pack_bf16x2(float a, float b) {
    return (uint)f32_to_bf16(a) | ((uint)f32_to_bf16(b) << 16);
}

// ------------------------------------------- fused cast f32->bf16 (q,k,v in one)
__global__ void cast3_f32_to_bf16(const float* __restrict__ q,
                                  const float* __restrict__ k,
                                  const float* __restrict__ v,
                                  ushort* __restrict__ xq,
                                  ushort* __restrict__ xk,
                                  ushort* __restrict__ xv, int n8) {
    const float* in  = blockIdx.z == 0 ? q  : (blockIdx.z == 1 ? k  : v);
    ushort*      out = blockIdx.z == 0 ? xq : (blockIdx.z == 1 ? xk : xv);
    int i = blockIdx.x * blockDim.x + threadIdx.x;
    const int stride = gridDim.x * blockDim.x;
    for (; i < n8; i += stride) {
        const float4 a = ((const float4*)in)[2 * i];
        const float4 b = ((const float4*)in)[2 * i + 1];
        uint4 o;
        o.x = (uint)f32_to_bf16(a.x) | ((uint)f32_to_bf16(a.y) << 16);
        o.y = (uint)f32_to_bf16(a.z) | ((uint)f32_to_bf16(a.w) << 16);
        o.z = (uint)f32_to_bf16(b.x) | ((uint)f32_to_bf16(b.y) << 16);
        o.w = (uint)f32_to_bf16(b.z) | ((uint)f32_to_bf16(b.w) << 16);
        ((uint4*)out)[i] = o;
    }
}

// ---------------------- fused W[K][N] f32 -> Wt[N][K] bf16 for all four weights
// grid.x block ranges: [0,64) Wq, [64,80) Wk, [80,96) Wv, [96,160) Wo. K=2048.
__global__ void transpose_cast4(const float* __restrict__ Wq,
                                const float* __restrict__ Wk,
                                const float* __restrict__ Wv,
                                const float* __restrict__ Wo,
                                ushort* __restrict__ Wqt, ushort* __restrict__ Wkt,
                                ushort* __restrict__ Wvt, ushort* __restrict__ Wot) {
    __shared__ float t[32][33];
    int bx = blockIdx.x;
    const float* W; ushort* Wt; int N;
    if (bx < 64)      { W = Wq; Wt = Wqt; N = 2048; }
    else if (bx < 80) { W = Wk; Wt = Wkt; N = 512;  bx -= 64; }
    else if (bx < 96) { W = Wv; Wt = Wvt; N = 512;  bx -= 80; }
    else              { W = Wo; Wt = Wot; N = 2048; bx -= 96; }
    const int n0 = bx * 32, k0 = blockIdx.y * 32;
    const int tx = threadIdx.x, ty = threadIdx.y;   // 32 x 8
#pragma unroll
    for (int i = 0; i < 4; ++i)
        t[ty + 8 * i][tx] = W[(size_t)(k0 + ty + 8 * i) * N + n0 + tx];
    __syncthreads();
#pragma unroll
    for (int i = 0; i < 4; ++i)
        Wt[(size_t)(n0 + ty + 8 * i) * 2048 + k0 + tx] = f32_to_bf16(t[tx][ty + 8 * i]);
}

// ------------------------------------------------------------- bf16 MFMA GEMM
// C[M][N] = (A[M][K] @ Bt[N][K]^T + bias) * scale.  128(M)x64(N) tile, 4 waves
// stacked in M (each: 32 rows x 64 cols = 2x4 frags of mfma_f32_16x16x32_bf16).
// BK=64, LDS row stride 72 shorts (144B -> 2-way alias only).
// DEPTH-2 register prefetch: two named reg sets X/Y (no runtime indexing,
// rule #20); tile k+2's loads are issued during tile k's compute, so each
// load has ~2 full compute phases (~1000+ cy) in flight before its ds_write
// — covers HBM-miss latency (~900 cy), not just L2 hits.  Single LDS buffer;
// requires K % 128 == 0.
// MODE: 0 = bf16 C, 1 = f32 C, 2 = bf16 C^T (V^T, output stride S_LEN) via LDS.
template <int MODE>
__device__ __forceinline__ void gemm_body_128x64(
        const ushort* __restrict__ A, const ushort* __restrict__ Bt,
        const float* __restrict__ bias, void* __restrict__ Cv,
        ushort* As, ushort* Bs, ushort* Ts, int N, int K, float scale,
        int bx, int by) {
    const int tid  = threadIdx.x;
    const int lane = tid & 63, wave = tid >> 6;
    const int l15 = lane & 15, quad = lane >> 4;
    const int row0 = by * 128, col0 = bx * 64;

    f32x4 acc[2][4];
#pragma unroll
    for (int i = 0; i < 2; ++i)
#pragma unroll
        for (int j = 0; j < 4; ++j) { f32x4 z = {0.f,0.f,0.f,0.f}; acc[i][j] = z; }

    // staging coords (BK=64): A 128x64 (4 b128/thread), B 64x64 (2 b128/thread)
    const int ar = tid >> 1, ak = (tid & 1) * 32;
    const int br = tid >> 2, bk = (tid & 3) * 16;
    const ushort* aptr = A  + (size_t)(row0 + ar) * K + ak;
    const ushort* bptr = Bt + (size_t)(col0 + br) * K + bk;

    // set X <- tile 0, set Y <- tile 1 (k=64)
    bf16x8 xa0 = *(const bf16x8*)(aptr);
    bf16x8 xa1 = *(const bf16x8*)(aptr + 8);
    bf16x8 xa2 = *(const bf16x8*)(aptr + 16);
    bf16x8 xa3 = *(const bf16x8*)(aptr + 24);
    bf16x8 xb0 = *(const bf16x8*)(bptr);
    bf16x8 xb1 = *(const bf16x8*)(bptr + 8);
    bf16x8 ya0 = *(const bf16x8*)(aptr + 64);
    bf16x8 ya1 = *(const bf16x8*)(aptr + 72);
    bf16x8 ya2 = *(const bf16x8*)(aptr + 80);
    bf16x8 ya3 = *(const bf16x8*)(aptr + 88);
    bf16x8 yb0 = *(const bf16x8*)(bptr + 64);
    bf16x8 yb1 = *(const bf16x8*)(bptr + 72);

    for (int k0 = 0; k0 < K; k0 += 128) {
        // ---------------- sub-step 0: tile k0 (set X)
        __syncthreads();
        *(bf16x8*)&As[ar * 72 + ak]      = xa0;
        *(bf16x8*)&As[ar * 72 + ak + 8]  = xa1;
        *(bf16x8*)&As[ar * 72 + ak + 16] = xa2;
        *(bf16x8*)&As[ar * 72 + ak + 24] = xa3;
        *(bf16x8*)&Bs[br * 72 + bk]      = xb0;
        *(bf16x8*)&Bs[br * 72 + bk + 8]  = xb1;
        __syncthreads();
        if (k0 + 128 < K) {                       // X <- tile k0+128
            xa0 = *(const bf16x8*)(aptr + k0 + 128);
            xa1 = *(const bf16x8*)(aptr + k0 + 136);
            xa2 = *(const bf16x8*)(aptr + k0 + 144);
            xa3 = *(const bf16x8*)(aptr + k0 + 152);
            xb0 = *(const bf16x8*)(bptr + k0 + 128);
            xb1 = *(const bf16x8*)(bptr + k0 + 136);
        }
#pragma unroll
        for (int kk = 0; kk < 2; ++kk) {
            bf16x8 af[2], bf[4];
#pragma unroll
            for (int mi = 0; mi < 2; ++mi)
                af[mi] = *(const bf16x8*)&As[(wave * 32 + mi * 16 + l15) * 72 + kk * 32 + quad * 8];
#pragma unroll
            for (int ni = 0; ni < 4; ++ni)
                bf[ni] = *(const bf16x8*)&Bs[(ni * 16 + l15) * 72 + kk * 32 + quad * 8];
#pragma unroll
            for (int mi = 0; mi < 2; ++mi)
#pragma unroll
                for (int ni = 0; ni < 4; ++ni)
                    acc[mi][ni] = __builtin_amdgcn_mfma_f32_16x16x32_bf16(
                        af[mi], bf[ni], acc[mi][ni], 0, 0, 0);
        }

        // ---------------- sub-step 1: tile k0+64 (set Y)
        __syncthreads();
        *(bf16x8*)&As[ar * 72 + ak]      = ya0;
        *(bf16x8*)&As[ar * 72 + ak + 8]  = ya1;
        *(bf16x8*)&As[ar * 72 + ak + 16] = ya2;
        *(bf16x8*)&As[ar * 72 + ak + 24] = ya3;
        *(bf16x8*)&Bs[br * 72 + bk]      = yb0;
        *(bf16x8*)&Bs[br * 72 + bk + 8]  = yb1;
        __syncthreads();
        if (k0 + 192 < K) {                       // Y <- tile k0+192
            ya0 = *(const bf16x8*)(aptr + k0 + 192);
            ya1 = *(const bf16x8*)(aptr + k0 + 200);
            ya2 = *(const bf16x8*)(aptr + k0 + 208);
            ya3 = *(const bf16x8*)(aptr + k0 + 216);
            yb0 = *(const bf16x8*)(bptr + k0 + 192);
            yb1 = *(const bf16x8*)(bptr + k0 + 200);
        }
#pragma unroll
        for (int kk = 0; kk < 2; ++kk) {
            bf16x8 af[2], bf[4];
#pragma unroll
            for (int mi = 0; mi < 2; ++mi)
                af[mi] = *(const bf16x8*)&As[(wave * 32 + mi * 16 + l15) * 72 + kk * 32 + quad * 8];
#pragma unroll
            for (int ni = 0; ni < 4; ++ni)
                bf[ni] = *(const bf16x8*)&Bs[(ni * 16 + l15) * 72 + kk * 32 + quad * 8];
#pragma unroll
            for (int mi = 0; mi < 2; ++mi)
#pragma unroll
                for (int ni = 0; ni < 4; ++ni)
                    acc[mi][ni] = __builtin_amdgcn_mfma_f32_16x16x32_bf16(
                        af[mi], bf[ni], acc[mi][ni], 0, 0, 0);
        }
    }

    if (MODE == 2) {
        // ---- V^T epilogue: stage 128(s) x 64(v) accs into LDS as [v][s],
        // then coalesced store to Cv[v][s] with row stride S_LEN.
        __syncthreads();                  // last K-step's LDS reads done
#pragma unroll
        for (int mi = 0; mi < 2; ++mi)
#pragma unroll
            for (int ni = 0; ni < 4; ++ni) {
                const float bv = bias[col0 + ni * 16 + l15];
                const int lrow = wave * 32 + mi * 16 + quad * 4;   // mult of 4
                uint2 uu;
                uu.x = pack_bf16x2((acc[mi][ni][0] + bv) * scale,
                                   (acc[mi][ni][1] + bv) * scale);
                uu.y = pack_bf16x2((acc[mi][ni][2] + bv) * scale,
                                   (acc[mi][ni][3] + bv) * scale);
                *(uint2*)&Ts[(ni * 16 + l15) * 136 + lrow] = uu;
            }
        __syncthreads();
        const int v = tid >> 2, s0 = (tid & 3) * 32;
#pragma unroll
        for (int i = 0; i < 4; ++i) {
            const uint4 d = *(const uint4*)&Ts[v * 136 + s0 + 8 * i];
            *(uint4*)&((ushort*)Cv)[(size_t)(col0 + v) * S_LEN + row0 + s0 + 8 * i] = d;
        }
        return;
    }

#pragma unroll
    for (int mi = 0; mi < 2; ++mi)
#pragma unroll
        for (int ni = 0; ni < 4; ++ni) {
            const int col = col0 + ni * 16 + l15;
            const float bv = bias[col];
#pragma unroll
            for (int reg = 0; reg < 4; ++reg) {
                const int row = row0 + wave * 32 + mi * 16 + quad * 4 + reg;
                const float val = (acc[mi][ni][reg] + bv) * scale;
                if (MODE == 1)
                    ((float*)Cv)[(size_t)row * N + col] = val;
                else
                    ((ushort*)Cv)[(size_t)row * N + col] = f32_to_bf16(val);
            }
        }
}

// XCD-aware 2D-chunk decode for 512-block GEMMs (32 col-tiles x 16 row-tiles).
// Dispatch round-robins blocks over 8 XCDs (xcd = d & 7); give each XCD an
// 8x8 tile rect so it touches 8 A-panels (4 MB) + 8 B-panels (2 MB) ~ L2-sized.
__device__ __forceinline__ void xcd_decode_32x16(int d, int& bx, int& by) {
    const int xcd = d & 7, i = d >> 3;          // i in [0,64)
    bx = (xcd & 3) * 8 + (i & 7);
    by = (xcd >> 2) * 8 + (i >> 3);
}

// Q projection: [2048,2048]x[2048,2048], bf16 out, scale folded
__global__ __launch_bounds__(256) void gemm_q(
        const ushort* __restrict__ A, const ushort* __restrict__ Bt,
        const float* __restrict__ bias, ushort* __restrict__ Cv, int K,
        float scale) {
    __shared__ ushort smem[128 * 72 + 64 * 72];
    int bx, by; xcd_decode_32x16(blockIdx.x, bx, by);
    gemm_body_128x64<0>(A, Bt, bias, Cv, smem, smem + 128 * 72, nullptr,
                        2048, K, scale, bx, by);
}

// O projection: f32 out
__global__ __launch_bounds__(256) void gemm_o(
        const ushort* __restrict__ A, const ushort* __restrict__ Bt,
        const float* __restrict__ bias, float* __restrict__ Cv, int K) {
    __shared__ ushort smem[128 * 72 + 64 * 72];
    int bx, by; xcd_decode_32x16(blockIdx.x, bx, by);
    gemm_body_128x64<1>(A, Bt, bias, Cv, smem, smem + 128 * 72, nullptr,
                        2048, K, 1.0f, bx, by);
}

// K and V projections fused via gridDim.z; V writes V^T directly (MODE 2).
__global__ __launch_bounds__(256) void gemm_kv(
        const ushort* __restrict__ Xk, const ushort* __restrict__ Xv,
        const ushort* __restrict__ Wkt, const ushort* __restrict__ Wvt,
        const float* __restrict__ bk, const float* __restrict__ bv,
        ushort* __restrict__ Kb, ushort* __restrict__ Vtp, int K) {
    __shared__ ushort smem[128 * 72 + 64 * 72];   // 13824 shorts; Ts needs 8704
    ushort* As = smem;
    ushort* Bs = smem + 128 * 72;
    if (blockIdx.z == 0)
        gemm_body_128x64<0>(Xk, Wkt, bk, Kb, As, Bs, nullptr, 512, K, 1.0f,
                            blockIdx.x, blockIdx.y);
    else
        gemm_body_128x64<2>(Xv, Wvt, bv, Vtp, As, Bs, smem, 512, K, 1.0f,
                            blockIdx.x, blockIdx.y);
}

// ------------------------------------------------------ MFMA flash attention
// Grid (32, 16, 2): x = head, y = pair index, z = sel; block handles ONE
// 64-row q-tile: qt = z ? 31-y : y.  1024 blocks, 4 blocks/CU all-resident.
// Ordering (head fastest) keeps per-CU causal load balanced (66 j-tile-units
// per stride-256 class) and gives each XCD a 4-of-8 KV-group L2 footprint.
// 4 waves/block; wave owns a 16-row Q stripe.
//
// SWAPPED-OPERAND version: S^T = mfma(K_frag, Q_frag) puts q in the C-layout
// column (l15) — each lane owns ONE q row. Online-softmax state (m, l) is a
// single scalar per lane; row max/sum = 15 in-lane ops + 2 shfl_xor (16, 32).
// P^T packs into per-wave LDS as [q][key] (8B vector stores) and reads back
// contiguously as the PV B-frag. PV computes O^T = mfma(V^T_frag, P^T_frag);
// V^T LDS tile is already in A-frag layout. Scale (1/sqrt(dk) * log2e) is
// pre-folded into Q; exp = exp2. Defer-max rescale (T13).
__global__ __launch_bounds__(256) void gqa_attn_mfma(
        const ushort* __restrict__ Qb, const ushort* __restrict__ Kb,
        const ushort* __restrict__ Vt, ushort* __restrict__ Ab) {
    __shared__ ushort Ks[64 * 72];       // [key][d]
    __shared__ ushort Vs[64 * 72];       // [d][key]
    __shared__ ushort Ps[4][16 * 72];    // per-wave P^T as [q][key]

    const int h    = blockIdx.x, g = h >> 2;
    const int tid  = threadIdx.x;
    const int lane = tid & 63, wave = tid >> 6;
    const int l15  = lane & 15, quad = lane >> 4;
    const int NT   = S_LEN / 64;         // 32 q-tiles
    const float DEFER_THR = 11.5416f;    // 8 * log2(e)

    // per-thread staging coordinates (fixed across tiles)
    const int srow = tid >> 2, sch = tid & 3;
    const ushort* kbase = Kb + (size_t)srow * (NG * DK) + g * DK + sch * 16;
    const ushort* vbase = Vt + (size_t)(g * 64 + srow) * S_LEN + sch * 16;

    const int qt = blockIdx.z ? (NT - 1 - (int)blockIdx.y) : (int)blockIdx.y;
    const int qr = qt * 64 + wave * 16;          // wave's first q row

    // Q frags (scale pre-folded at projection time), d=0..31 / 32..63
    bf16x8 qa0, qa1;
    {
        const size_t base = (size_t)(qr + l15) * (NH * DK) + (size_t)h * DK + quad * 8;
        qa0 = *(const bf16x8*)&Qb[base];
        qa1 = *(const bf16x8*)&Qb[base + 32];
    }

    f32x4 o[4];                          // O^T: lane = q (l15); rows = d
#pragma unroll
    for (int dt = 0; dt < 4; ++dt) { f32x4 z = {0.f,0.f,0.f,0.f}; o[dt] = z; }
    float m = -1e30f;                    // per-lane (per-q) running max, log2 domain
    float l = 0.f;                       // per-lane running sum

    // preload tile 0
    bf16x8 kr0 = *(const bf16x8*)(kbase);
    bf16x8 kr1 = *(const bf16x8*)(kbase + 8);
    bf16x8 vr0 = *(const bf16x8*)(vbase);
    bf16x8 vr1 = *(const bf16x8*)(vbase + 8);

    for (int jt = 0; jt <= qt; ++jt) {
        __syncthreads();                 // prior LDS reads complete
        *(bf16x8*)&Ks[srow * 72 + sch * 16]     = kr0;
        *(bf16x8*)&Ks[srow * 72 + sch * 16 + 8] = kr1;
        *(bf16x8*)&Vs[srow * 72 + sch * 16]     = vr0;
        *(bf16x8*)&Vs[srow * 72 + sch * 16 + 8] = vr1;
        __syncthreads();

        // prefetch tile jt+1 (flies during compute below)
        if (jt < qt) {
            const size_t ko = (size_t)(jt + 1) * 64 * (NG * DK);
            const size_t vo = (size_t)(jt + 1) * 64;
            kr0 = *(const bf16x8*)(kbase + ko);
            kr1 = *(const bf16x8*)(kbase + ko + 8);
            vr0 = *(const bf16x8*)(vbase + vo);
            vr1 = *(const bf16x8*)(vbase + vo + 8);
        }

        // S^T = K Q^T : C-layout col = q (l15), row = key (quad*4+r, +16*kt)
        f32x4 s[4];
#pragma unroll
        for (int kt = 0; kt < 4; ++kt) {
            const bf16x8 kb0 = *(const bf16x8*)&Ks[(kt * 16 + l15) * 72 + quad * 8];
            const bf16x8 kb1 = *(const bf16x8*)&Ks[(kt * 16 + l15) * 72 + 32 + quad * 8];
            f32x4 acc = {0.f, 0.f, 0.f, 0.f};
            acc = __builtin_amdgcn_mfma_f32_16x16x32_bf16(kb0, qa0, acc, 0, 0, 0);
            acc = __builtin_amdgcn_mfma_f32_16x16x32_bf16(kb1, qa1, acc, 0, 0, 0);
            s[kt] = acc;
        }

        // causal mask (diagonal tile only; scale already folded into Q)
        if (jt == qt) {
            const int row = wave * 16 + l15;   // q within the 64-row tile
#pragma unroll
            for (int kt = 0; kt < 4; ++kt)
#pragma unroll
                for (int r = 0; r < 4; ++r) {
                    const int key = kt * 16 + quad * 4 + r;
                    if (key > row) s[kt][r] = -1e30f;
                }
        }

        // tile max for this q row: 15 in-lane + cross-quad (xor 16, 32)
        float pmax;
        {
            const float t0 = fmaxf(fmaxf(s[0][0], s[0][1]), fmaxf(s[0][2], s[0][3]));
            const float t1 = fmaxf(fmaxf(s[1][0], s[1][1]), fmaxf(s[1][2], s[1][3]));
            const float t2 = fmaxf(fmaxf(s[2][0], s[2][1]), fmaxf(s[2][2], s[2][3]));
            const float t3 = fmaxf(fmaxf(s[3][0], s[3][1]), fmaxf(s[3][2], s[3][3]));
            pmax = fmaxf(fmaxf(t0, t1), fmaxf(t2, t3));
        }
        pmax = fmaxf(pmax, __shfl_xor(pmax, 16, 64));
        pmax = fmaxf(pmax, __shfl_xor(pmax, 32, 64));

        // defer-max: only rescale when the tile max grew past threshold
        if (!__all(pmax - m <= DEFER_THR)) {
            const float mnew  = fmaxf(m, pmax);
            const float alpha = __builtin_amdgcn_exp2f(m - mnew);
            l *= alpha;
#pragma unroll
            for (int dt = 0; dt < 4; ++dt)
#pragma unroll
                for (int r = 0; r < 4; ++r) o[dt][r] *= alpha;
            m = mnew;
        }

        float p[4][4];
#pragma unroll
        for (int kt = 0; kt < 4; ++kt)
#pragma unroll
            for (int r = 0; r < 4; ++r)
                p[kt][r] = __builtin_amdgcn_exp2f(s[kt][r] - m);

        float rsum;
        {
            const float u0 = (p[0][0] + p[0][1]) + (p[0][2] + p[0][3]);
            const float u1 = (p[1][0] + p[1][1]) + (p[1][2] + p[1][3]);
            const float u2 = (p[2][0] + p[2][1]) + (p[2][2] + p[2][3]);
            const float u3 = (p[3][0] + p[3][1]) + (p[3][2] + p[3][3]);
            rsum = (u0 + u1) + (u2 + u3);
        }
        rsum += __shfl_xor(rsum, 16, 64);
        rsum += __shfl_xor(rsum, 32, 64);
        l += rsum;

        // P^T -> per-wave LDS [q][key]: 8B vector stores, contiguous keys
        ushort* Pw = &Ps[wave][0];
#pragma unroll
        for (int kt = 0; kt < 4; ++kt) {
            uint2 uu;
            uu.x = pack_bf16x2(p[kt][0], p[kt][1]);
            uu.y = pack_bf16x2(p[kt][2], p[kt][3]);
            *(uint2*)&Pw[l15 * 72 + kt * 16 + quad * 4] = uu;
        }
        const bf16x8 pa0 = *(const bf16x8*)&Pw[l15 * 72 + quad * 8];
        const bf16x8 pa1 = *(const bf16x8*)&Pw[l15 * 72 + 32 + quad * 8];

        // O^T += V^T P^T : A = V^T tile (already [d][key] in LDS), B = P^T
#pragma unroll
        for (int dt = 0; dt < 4; ++dt) {
            const bf16x8 vb0 = *(const bf16x8*)&Vs[(dt * 16 + l15) * 72 + quad * 8];
            const bf16x8 vb1 = *(const bf16x8*)&Vs[(dt * 16 + l15) * 72 + 32 + quad * 8];
            o[dt] = __builtin_amdgcn_mfma_f32_16x16x32_bf16(vb0, pa0, o[dt], 0, 0, 0);
            o[dt] = __builtin_amdgcn_mfma_f32_16x16x32_bf16(vb1, pa1, o[dt], 0, 0, 0);
        }
    }

    // epilogue: lane holds O^T[d = dt*16 + quad*4 + r][q = l15]
    const float invl = 1.0f / l;
#pragma unroll
    for (int dt = 0; dt < 4; ++dt) {
        uint2 uu;
        uu.x = pack_bf16x2(o[dt][0] * invl, o[dt][1] * invl);
        uu.y = pack_bf16x2(o[dt][2] * invl, o[dt][3] * invl);
        *(uint2*)&Ab[(size_t)(qr + l15) * (NH * DV) + (size_t)h * DV + dt * 16 + quad * 4] = uu;
    }
}

// ---------------------------------------------------------------------------
extern "C" void kernel_launch(void* const* d_in, const int* in_sizes, int n_in,
                              void* d_out, int out_size, void* d_ws, size_t ws_size,
                              hipStream_t stream) {
    const float* queries = (const float*)d_in[0];
    const float* keys    = (const float*)d_in[1];
    const float* values  = (const float*)d_in[2];
    const float* Wq      = (const float*)d_in[3];
    const float* bq      = (const float*)d_in[4];
    const float* Wk      = (const float*)d_in[5];
    const float* bk      = (const float*)d_in[6];
    const float* Wv      = (const float*)d_in[7];
    const float* bv      = (const float*)d_in[8];
    const float* Wo      = (const float*)d_in[9];
    const float* bo      = (const float*)d_in[10];
    float* out = (float*)d_out;

    const size_t MB = 1024 * 1024;
    unsigned char* w = (unsigned char*)d_ws;
    ushort* Xq  = (ushort*)(w + 0 * MB);    // [2048][2048] bf16
    ushort* Xk  = (ushort*)(w + 8 * MB);
    ushort* Xv  = (ushort*)(w + 16 * MB);
    ushort* Wqt = (ushort*)(w + 24 * MB);   // [2048][2048]
    ushort* Wkt = (ushort*)(w + 32 * MB);   // [512][2048]
    ushort* Wvt = (ushort*)(w + 34 * MB);
    ushort* Wot = (ushort*)(w + 36 * MB);   // [2048][2048]
    ushort* Qb  = (ushort*)(w + 44 * MB);   // [2048][2048]
    ushort* Kb  = (ushort*)(w + 52 * MB);   // [2048][512]
    ushort* Vtp = (ushort*)(w + 54 * MB);   // V^T [512][2048] (written directly)
    ushort* Ab  = (ushort*)(w + 56 * MB);   // [2048][2048]

    const int n8 = (S_LEN * DMODEL) / 8;
    cast3_f32_to_bf16<<<dim3(1024, 1, 3), 256, 0, stream>>>(
        queries, keys, values, Xq, Xk, Xv, n8);

    dim3 tb(32, 8);
    transpose_cast4<<<dim3(160, 64), tb, 0, stream>>>(
        Wq, Wk, Wv, Wo, Wqt, Wkt, Wvt, Wot);

    // Q projection (XCD-swizzled); softmax scale * log2(e) folded into Q
    const float QSCALE = 0.125f * 1.44269504f;
    gemm_q<<<512, 256, 0, stream>>>(Xq, Wqt, bq, Qb, DMODEL, QSCALE);

    // K and V projections fused (z=0: K, z=1: V -> V^T direct)
    gemm_kv<<<dim3(8, 16, 2), 256, 0, stream>>>(
        Xk, Xv, Wkt, Wvt, bk, bv, Kb, Vtp, DMODEL);

    // attention: 1024 blocks, one q-tile each, stride-256-balanced ordering
    gqa_attn_mfma<<<dim3(32, 16, 2), 256, 0, stream>>>(Qb, Kb, Vtp, Ab);

    // O projection (XCD-swizzled): [2048,2048] @ [2048,2048] -> f32 out
    gemm_o<<<512, 256, 0, stream>>>(Ab, Wot, bo, out, DMODEL);
}

// Round 10
// 267.959 us; speedup vs baseline: 1.1931x; 1.0058x over previous
//
#include <hip/hip_runtime.h>
#include <hip/hip_bf16.h>

#define S_LEN  2048
#define DMODEL 2048
#define NH     32
#define NG     8
#define DK     64
#define DV     64

typedef short bf16x8 __attribute__((ext_vector_type(8)));
typedef float f32x4  __attribute__((ext_vector_type(4)));

__device__ __forceinline__ ushort f32_to_bf16(float f) {
    uint u = __float_as_uint(f);
    return (ushort)((u + 0x7fffu + ((u >> 16) & 1u)) >> 16);   // RNE
}
__device__ __forceinline__ float bf16_to_f32(ushort h) {
    return __uint_as_float(((uint)h) << 16);
}
__device__ __forceinline__ uint pack_bf16x2(float a, float b) {
    return (uint)f32_to_bf16(a) | ((uint)f32_to_bf16(b) << 16);
}

// ------------------------------------------- fused cast f32->bf16 (q,k,v in one)
__global__ void cast3_f32_to_bf16(const float* __restrict__ q,
                                  const float* __restrict__ k,
                                  const float* __restrict__ v,
                                  ushort* __restrict__ xq,
                                  ushort* __restrict__ xk,
                                  ushort* __restrict__ xv, int n8) {
    const float* in  = blockIdx.z == 0 ? q  : (blockIdx.z == 1 ? k  : v);
    ushort*      out = blockIdx.z == 0 ? xq : (blockIdx.z == 1 ? xk : xv);
    int i = blockIdx.x * blockDim.x + threadIdx.x;
    const int stride = gridDim.x * blockDim.x;
    for (; i < n8; i += stride) {
        const float4 a = ((const float4*)in)[2 * i];
        const float4 b = ((const float4*)in)[2 * i + 1];
        uint4 o;
        o.x = (uint)f32_to_bf16(a.x) | ((uint)f32_to_bf16(a.y) << 16);
        o.y = (uint)f32_to_bf16(a.z) | ((uint)f32_to_bf16(a.w) << 16);
        o.z = (uint)f32_to_bf16(b.x) | ((uint)f32_to_bf16(b.y) << 16);
        o.w = (uint)f32_to_bf16(b.z) | ((uint)f32_to_bf16(b.w) << 16);
        ((uint4*)out)[i] = o;
    }
}

// ---------------------- fused W[K][N] f32 -> Wt[N][K] bf16 for all four weights
// grid.x block ranges: [0,64) Wq, [64,80) Wk, [80,96) Wv, [96,160) Wo. K=2048.
__global__ void transpose_cast4(const float* __restrict__ Wq,
                                const float* __restrict__ Wk,
                                const float* __restrict__ Wv,
                                const float* __restrict__ Wo,
                                ushort* __restrict__ Wqt, ushort* __restrict__ Wkt,
                                ushort* __restrict__ Wvt, ushort* __restrict__ Wot) {
    __shared__ float t[32][33];
    int bx = blockIdx.x;
    const float* W; ushort* Wt; int N;
    if (bx < 64)      { W = Wq; Wt = Wqt; N = 2048; }
    else if (bx < 80) { W = Wk; Wt = Wkt; N = 512;  bx -= 64; }
    else if (bx < 96) { W = Wv; Wt = Wvt; N = 512;  bx -= 80; }
    else              { W = Wo; Wt = Wot; N = 2048; bx -= 96; }
    const int n0 = bx * 32, k0 = blockIdx.y * 32;
    const int tx = threadIdx.x, ty = threadIdx.y;   // 32 x 8
#pragma unroll
    for (int i = 0; i < 4; ++i)
        t[ty + 8 * i][tx] = W[(size_t)(k0 + ty + 8 * i) * N + n0 + tx];
    __syncthreads();
#pragma unroll
    for (int i = 0; i < 4; ++i)
        Wt[(size_t)(n0 + ty + 8 * i) * 2048 + k0 + tx] = f32_to_bf16(t[tx][ty + 8 * i]);
}

// ------------------------------------------------------------- bf16 MFMA GEMM
// C[M][N] = (A[M][K] @ Bt[N][K]^T + bias) * scale.  128(M)x64(N) tile, 4 waves
// stacked in M (each: 32 rows x 64 cols = 2x4 frags of mfma_f32_16x16x32_bf16).
// BK=64, LDS row stride 72 shorts (144B -> 2-way alias only).  Depth-2
// register prefetch (named sets X/Y).  Requires K % 128 == 0.
// MODE: 0 = bf16 C, 1 = f32 C, 2 = bf16 C^T (V^T, output stride S_LEN) via LDS.
template <int MODE>
__device__ __forceinline__ void gemm_body_128x64(
        const ushort* __restrict__ A, const ushort* __restrict__ Bt,
        const float* __restrict__ bias, void* __restrict__ Cv,
        ushort* As, ushort* Bs, ushort* Ts, int N, int K, float scale,
        int bx, int by) {
    const int tid  = threadIdx.x;
    const int lane = tid & 63, wave = tid >> 6;
    const int l15 = lane & 15, quad = lane >> 4;
    const int row0 = by * 128, col0 = bx * 64;

    f32x4 acc[2][4];
#pragma unroll
    for (int i = 0; i < 2; ++i)
#pragma unroll
        for (int j = 0; j < 4; ++j) { f32x4 z = {0.f,0.f,0.f,0.f}; acc[i][j] = z; }

    // staging coords (BK=64): A 128x64 (4 b128/thread), B 64x64 (2 b128/thread)
    const int ar = tid >> 1, ak = (tid & 1) * 32;
    const int br = tid >> 2, bk = (tid & 3) * 16;
    const ushort* aptr = A  + (size_t)(row0 + ar) * K + ak;
    const ushort* bptr = Bt + (size_t)(col0 + br) * K + bk;

    // set X <- tile 0, set Y <- tile 1 (k=64)
    bf16x8 xa0 = *(const bf16x8*)(aptr);
    bf16x8 xa1 = *(const bf16x8*)(aptr + 8);
    bf16x8 xa2 = *(const bf16x8*)(aptr + 16);
    bf16x8 xa3 = *(const bf16x8*)(aptr + 24);
    bf16x8 xb0 = *(const bf16x8*)(bptr);
    bf16x8 xb1 = *(const bf16x8*)(bptr + 8);
    bf16x8 ya0 = *(const bf16x8*)(aptr + 64);
    bf16x8 ya1 = *(const bf16x8*)(aptr + 72);
    bf16x8 ya2 = *(const bf16x8*)(aptr + 80);
    bf16x8 ya3 = *(const bf16x8*)(aptr + 88);
    bf16x8 yb0 = *(const bf16x8*)(bptr + 64);
    bf16x8 yb1 = *(const bf16x8*)(bptr + 72);

    for (int k0 = 0; k0 < K; k0 += 128) {
        // ---------------- sub-step 0: tile k0 (set X)
        __syncthreads();
        *(bf16x8*)&As[ar * 72 + ak]      = xa0;
        *(bf16x8*)&As[ar * 72 + ak + 8]  = xa1;
        *(bf16x8*)&As[ar * 72 + ak + 16] = xa2;
        *(bf16x8*)&As[ar * 72 + ak + 24] = xa3;
        *(bf16x8*)&Bs[br * 72 + bk]      = xb0;
        *(bf16x8*)&Bs[br * 72 + bk + 8]  = xb1;
        __syncthreads();
        if (k0 + 128 < K) {                       // X <- tile k0+128
            xa0 = *(const bf16x8*)(aptr + k0 + 128);
            xa1 = *(const bf16x8*)(aptr + k0 + 136);
            xa2 = *(const bf16x8*)(aptr + k0 + 144);
            xa3 = *(const bf16x8*)(aptr + k0 + 152);
            xb0 = *(const bf16x8*)(bptr + k0 + 128);
            xb1 = *(const bf16x8*)(bptr + k0 + 136);
        }
#pragma unroll
        for (int kk = 0; kk < 2; ++kk) {
            bf16x8 af[2], bf[4];
#pragma unroll
            for (int mi = 0; mi < 2; ++mi)
                af[mi] = *(const bf16x8*)&As[(wave * 32 + mi * 16 + l15) * 72 + kk * 32 + quad * 8];
#pragma unroll
            for (int ni = 0; ni < 4; ++ni)
                bf[ni] = *(const bf16x8*)&Bs[(ni * 16 + l15) * 72 + kk * 32 + quad * 8];
#pragma unroll
            for (int mi = 0; mi < 2; ++mi)
#pragma unroll
                for (int ni = 0; ni < 4; ++ni)
                    acc[mi][ni] = __builtin_amdgcn_mfma_f32_16x16x32_bf16(
                        af[mi], bf[ni], acc[mi][ni], 0, 0, 0);
        }

        // ---------------- sub-step 1: tile k0+64 (set Y)
        __syncthreads();
        *(bf16x8*)&As[ar * 72 + ak]      = ya0;
        *(bf16x8*)&As[ar * 72 + ak + 8]  = ya1;
        *(bf16x8*)&As[ar * 72 + ak + 16] = ya2;
        *(bf16x8*)&As[ar * 72 + ak + 24] = ya3;
        *(bf16x8*)&Bs[br * 72 + bk]      = yb0;
        *(bf16x8*)&Bs[br * 72 + bk + 8]  = yb1;
        __syncthreads();
        if (k0 + 192 < K) {                       // Y <- tile k0+192
            ya0 = *(const bf16x8*)(aptr + k0 + 192);
            ya1 = *(const bf16x8*)(aptr + k0 + 200);
            ya2 = *(const bf16x8*)(aptr + k0 + 208);
            ya3 = *(const bf16x8*)(aptr + k0 + 216);
            yb0 = *(const bf16x8*)(bptr + k0 + 192);
            yb1 = *(const bf16x8*)(bptr + k0 + 200);
        }
#pragma unroll
        for (int kk = 0; kk < 2; ++kk) {
            bf16x8 af[2], bf[4];
#pragma unroll
            for (int mi = 0; mi < 2; ++mi)
                af[mi] = *(const bf16x8*)&As[(wave * 32 + mi * 16 + l15) * 72 + kk * 32 + quad * 8];
#pragma unroll
            for (int ni = 0; ni < 4; ++ni)
                bf[ni] = *(const bf16x8*)&Bs[(ni * 16 + l15) * 72 + kk * 32 + quad * 8];
#pragma unroll
            for (int mi = 0; mi < 2; ++mi)
#pragma unroll
                for (int ni = 0; ni < 4; ++ni)
                    acc[mi][ni] = __builtin_amdgcn_mfma_f32_16x16x32_bf16(
                        af[mi], bf[ni], acc[mi][ni], 0, 0, 0);
        }
    }

    if (MODE == 2) {
        // ---- V^T epilogue: stage 128(s) x 64(v) accs into LDS as [v][s],
        // then coalesced store to Cv[v][s] with row stride S_LEN.
        __syncthreads();                  // last K-step's LDS reads done
#pragma unroll
        for (int mi = 0; mi < 2; ++mi)
#pragma unroll
            for (int ni = 0; ni < 4; ++ni) {
                const float bv = bias[col0 + ni * 16 + l15];
                const int lrow = wave * 32 + mi * 16 + quad * 4;   // mult of 4
                uint2 uu;
                uu.x = pack_bf16x2((acc[mi][ni][0] + bv) * scale,
                                   (acc[mi][ni][1] + bv) * scale);
                uu.y = pack_bf16x2((acc[mi][ni][2] + bv) * scale,
                                   (acc[mi][ni][3] + bv) * scale);
                *(uint2*)&Ts[(ni * 16 + l15) * 136 + lrow] = uu;
            }
        __syncthreads();
        const int v = tid >> 2, s0 = (tid & 3) * 32;
#pragma unroll
        for (int i = 0; i < 4; ++i) {
            const uint4 d = *(const uint4*)&Ts[v * 136 + s0 + 8 * i];
            *(uint4*)&((ushort*)Cv)[(size_t)(col0 + v) * S_LEN + row0 + s0 + 8 * i] = d;
        }
        return;
    }

#pragma unroll
    for (int mi = 0; mi < 2; ++mi)
#pragma unroll
        for (int ni = 0; ni < 4; ++ni) {
            const int col = col0 + ni * 16 + l15;
            const float bv = bias[col];
#pragma unroll
            for (int reg = 0; reg < 4; ++reg) {
                const int row = row0 + wave * 32 + mi * 16 + quad * 4 + reg;
                const float val = (acc[mi][ni][reg] + bv) * scale;
                if (MODE == 1)
                    ((float*)Cv)[(size_t)row * N + col] = val;
                else
                    ((ushort*)Cv)[(size_t)row * N + col] = f32_to_bf16(val);
            }
        }
}

// XCD-aware 2D-chunk decode for 512-block GEMMs (32 col-tiles x 16 row-tiles).
__device__ __forceinline__ void xcd_decode_32x16(int d, int& bx, int& by) {
    const int xcd = d & 7, i = d >> 3;          // i in [0,64)
    bx = (xcd & 3) * 8 + (i & 7);
    by = (xcd >> 2) * 8 + (i >> 3);
}

// Q projection: [2048,2048]x[2048,2048], bf16 out, scale folded
__global__ __launch_bounds__(256) void gemm_q(
        const ushort* __restrict__ A, const ushort* __restrict__ Bt,
        const float* __restrict__ bias, ushort* __restrict__ Cv, int K,
        float scale) {
    __shared__ ushort smem[128 * 72 + 64 * 72];
    int bx, by; xcd_decode_32x16(blockIdx.x, bx, by);
    gemm_body_128x64<0>(A, Bt, bias, Cv, smem, smem + 128 * 72, nullptr,
                        2048, K, scale, bx, by);
}

// O projection: f32 out
__global__ __launch_bounds__(256) void gemm_o(
        const ushort* __restrict__ A, const ushort* __restrict__ Bt,
        const float* __restrict__ bias, float* __restrict__ Cv, int K) {
    __shared__ ushort smem[128 * 72 + 64 * 72];
    int bx, by; xcd_decode_32x16(blockIdx.x, bx, by);
    gemm_body_128x64<1>(A, Bt, bias, Cv, smem, smem + 128 * 72, nullptr,
                        2048, K, 1.0f, bx, by);
}

// K and V projections fused via gridDim.z; V writes V^T directly (MODE 2).
__global__ __launch_bounds__(256) void gemm_kv(
        const ushort* __restrict__ Xk, const ushort* __restrict__ Xv,
        const ushort* __restrict__ Wkt, const ushort* __restrict__ Wvt,
        const float* __restrict__ bk, const float* __restrict__ bv,
        ushort* __restrict__ Kb, ushort* __restrict__ Vtp, int K) {
    __shared__ ushort smem[128 * 72 + 64 * 72];   // 13824 shorts; Ts needs 8704
    ushort* As = smem;
    ushort* Bs = smem + 128 * 72;
    if (blockIdx.z == 0)
        gemm_body_128x64<0>(Xk, Wkt, bk, Kb, As, Bs, nullptr, 512, K, 1.0f,
                            blockIdx.x, blockIdx.y);
    else
        gemm_body_128x64<2>(Xv, Wvt, bv, Vtp, As, Bs, smem, 512, K, 1.0f,
                            blockIdx.x, blockIdx.y);
}

// ------------------------------------------------------ MFMA flash attention
// Grid (32 h, 16 y), 512 threads = 8 waves.  Block owns the paired q-tiles
// {y, 31-y} (33 causal units).  PARITY SPLIT-K: wave-group pg=0 (waves 0-3)
// processes even j-tiles, pg=1 (waves 4-7) odd j-tiles, each with its own
// K/V LDS buffers and independent online-softmax state.  Iterations per pair
// = ceil((y+1)/2) + ceil((32-y)/2) = 17 for EVERY y -> all 512 blocks have
// identical duration; 2 blocks/CU (55.3 KB LDS) sustain 16 waves/CU for the
// whole dispatch (vs 8.25 avg with decaying unequal blocks).  Group partials
// merge IN-BLOCK per q-tile via LDS scratch (reusing the dead K buffers):
// M=max(m0,m1), L=l0*2^(m0-M)+l1*2^(m1-M), O=(O0*2^(m0-M)+O1*2^(m1-M))/L.
// Empty-partial edge (qt=0, pg=1): exp2(-1e30-m0) underflows to 0 -> no-op.
//
// SWAPPED-OPERAND core (unchanged): S^T = mfma(K,Q) puts q in the C-layout
// column; m,l scalar per lane; P^T via per-wave LDS; O^T = mfma(V^T,P^T).
// Scale (1/sqrt(dk)*log2e) pre-folded into Q; exp = exp2; defer-max (T13).
__global__ __launch_bounds__(512) void gqa_attn_mfma(
        const ushort* __restrict__ Qb, const ushort* __restrict__ Kb,
        const ushort* __restrict__ Vt, ushort* __restrict__ Ab) {
    __shared__ ushort sm[27648];         // 55296 B total
    // carve: Ks[pg] @ pg*4608, Vs[pg] @ 9216+pg*4608, Ps[wave] @ 18432+wave*1152
    // merge scratch = first 18432 B (Ks0+Ks1 region), barrier-ordered reuse.

    const int h    = blockIdx.x, g = h >> 2;     // head, KV group
    const int y    = blockIdx.y;
    const int tid  = threadIdx.x;
    const int lane = tid & 63, wave = tid >> 6;  // wave 0..7
    const int pg   = wave >> 2;                  // parity group 0/1
    const int l15  = lane & 15, quad = lane >> 4;
    const float DEFER_THR = 11.5416f;            // 8 * log2(e)

    ushort* Ksg = sm + pg * 4608;
    ushort* Vsg = sm + 9216 + pg * 4608;
    ushort* Pw  = sm + 18432 + wave * 1152;
    float*  scr = (float*)sm;                    // 4608 floats = 18432 B

    // group-local staging coords (256 threads per group)
    const int gtid = tid & 255;
    const int srow = gtid >> 2, sch = gtid & 3;
    const ushort* kbase = Kb + (size_t)srow * (NG * DK) + g * DK + sch * 16;
    const ushort* vbase = Vt + (size_t)(g * 64 + srow) * S_LEN + sch * 16;
    const size_t kstep = (size_t)64 * (NG * DK);

    for (int sel = 0; sel < 2; ++sel) {
        const int qt = sel ? (31 - y) : y;
        const int qr = qt * 64 + (wave & 3) * 16;    // wave's first q row

        // Q frags (scale pre-folded), d=0..31 / 32..63
        bf16x8 qa0, qa1;
        {
            const size_t base = (size_t)(qr + l15) * (NH * DK) + (size_t)h * DK + quad * 8;
            qa0 = *(const bf16x8*)&Qb[base];
            qa1 = *(const bf16x8*)&Qb[base + 32];
        }

        f32x4 o[4];                      // O^T partial: lane = q (l15); rows = d
#pragma unroll
        for (int dt = 0; dt < 4; ++dt) { f32x4 z = {0.f,0.f,0.f,0.f}; o[dt] = z; }
        float m = -1e30f;                // per-lane running max (log2 domain)
        float l = 0.f;                   // per-lane running sum

        // preload this group's tile 0 (j = pg; always in-bounds in memory)
        bf16x8 kr0 = *(const bf16x8*)(kbase + pg * kstep);
        bf16x8 kr1 = *(const bf16x8*)(kbase + pg * kstep + 8);
        bf16x8 vr0 = *(const bf16x8*)(vbase + pg * 64);
        bf16x8 vr1 = *(const bf16x8*)(vbase + pg * 64 + 8);

        const int iters = (qt >> 1) + 1;             // ceil((qt+1)/2)
        for (int it = 0; it < iters; ++it) {
            const int j = 2 * it + pg;               // this group's j-tile

            __syncthreads();             // prior LDS reads (incl. merge) done
            *(bf16x8*)&Ksg[srow * 72 + sch * 16]     = kr0;
            *(bf16x8*)&Ksg[srow * 72 + sch * 16 + 8] = kr1;
            *(bf16x8*)&Vsg[srow * 72 + sch * 16]     = vr0;
            *(bf16x8*)&Vsg[srow * 72 + sch * 16 + 8] = vr1;
            __syncthreads();

            // prefetch this group's next tile (j+2)
            if (j + 2 <= qt) {
                const size_t ko = (size_t)(j + 2) * kstep;
                const size_t vo = (size_t)(j + 2) * 64;
                kr0 = *(const bf16x8*)(kbase + ko);
                kr1 = *(const bf16x8*)(kbase + ko + 8);
                vr0 = *(const bf16x8*)(vbase + vo);
                vr1 = *(const bf16x8*)(vbase + vo + 8);
            }

            if (j <= qt) {               // group-uniform predicate
                // S^T = K Q^T
                f32x4 s[4];
#pragma unroll
                for (int kt = 0; kt < 4; ++kt) {
                    const bf16x8 kb0 = *(const bf16x8*)&Ksg[(kt * 16 + l15) * 72 + quad * 8];
                    const bf16x8 kb1 = *(const bf16x8*)&Ksg[(kt * 16 + l15) * 72 + 32 + quad * 8];
                    f32x4 acc = {0.f, 0.f, 0.f, 0.f};
                    acc = __builtin_amdgcn_mfma_f32_16x16x32_bf16(kb0, qa0, acc, 0, 0, 0);
                    acc = __builtin_amdgcn_mfma_f32_16x16x32_bf16(kb1, qa1, acc, 0, 0, 0);
                    s[kt] = acc;
                }

                // causal mask (diagonal tile only)
                if (j == qt) {
                    const int row = (wave & 3) * 16 + l15;
#pragma unroll
                    for (int kt = 0; kt < 4; ++kt)
#pragma unroll
                        for (int r = 0; r < 4; ++r) {
                            const int key = kt * 16 + quad * 4 + r;
                            if (key > row) s[kt][r] = -1e30f;
                        }
                }

                // tile max: 15 in-lane + cross-quad (xor 16, 32)
                float pmax;
                {
                    const float t0 = fmaxf(fmaxf(s[0][0], s[0][1]), fmaxf(s[0][2], s[0][3]));
                    const float t1 = fmaxf(fmaxf(s[1][0], s[1][1]), fmaxf(s[1][2], s[1][3]));
                    const float t2 = fmaxf(fmaxf(s[2][0], s[2][1]), fmaxf(s[2][2], s[2][3]));
                    const float t3 = fmaxf(fmaxf(s[3][0], s[3][1]), fmaxf(s[3][2], s[3][3]));
                    pmax = fmaxf(fmaxf(t0, t1), fmaxf(t2, t3));
                }
                pmax = fmaxf(pmax, __shfl_xor(pmax, 16, 64));
                pmax = fmaxf(pmax, __shfl_xor(pmax, 32, 64));

                // defer-max rescale
                if (!__all(pmax - m <= DEFER_THR)) {
                    const float mnew  = fmaxf(m, pmax);
                    const float alpha = __builtin_amdgcn_exp2f(m - mnew);
                    l *= alpha;
#pragma unroll
                    for (int dt = 0; dt < 4; ++dt)
#pragma unroll
                        for (int r = 0; r < 4; ++r) o[dt][r] *= alpha;
                    m = mnew;
                }

                float p[4][4];
#pragma unroll
                for (int kt = 0; kt < 4; ++kt)
#pragma unroll
                    for (int r = 0; r < 4; ++r)
                        p[kt][r] = __builtin_amdgcn_exp2f(s[kt][r] - m);

                float rsum;
                {
                    const float u0 = (p[0][0] + p[0][1]) + (p[0][2] + p[0][3]);
                    const float u1 = (p[1][0] + p[1][1]) + (p[1][2] + p[1][3]);
                    const float u2 = (p[2][0] + p[2][1]) + (p[2][2] + p[2][3]);
                    const float u3 = (p[3][0] + p[3][1]) + (p[3][2] + p[3][3]);
                    rsum = (u0 + u1) + (u2 + u3);
                }
                rsum += __shfl_xor(rsum, 16, 64);
                rsum += __shfl_xor(rsum, 32, 64);
                l += rsum;

                // P^T -> per-wave LDS [q][key]
#pragma unroll
                for (int kt = 0; kt < 4; ++kt) {
                    uint2 uu;
                    uu.x = pack_bf16x2(p[kt][0], p[kt][1]);
                    uu.y = pack_bf16x2(p[kt][2], p[kt][3]);
                    *(uint2*)&Pw[l15 * 72 + kt * 16 + quad * 4] = uu;
                }
                const bf16x8 pa0 = *(const bf16x8*)&Pw[l15 * 72 + quad * 8];
                const bf16x8 pa1 = *(const bf16x8*)&Pw[l15 * 72 + 32 + quad * 8];

                // O^T += V^T P^T
#pragma unroll
                for (int dt = 0; dt < 4; ++dt) {
                    const bf16x8 vb0 = *(const bf16x8*)&Vsg[(dt * 16 + l15) * 72 + quad * 8];
                    const bf16x8 vb1 = *(const bf16x8*)&Vsg[(dt * 16 + l15) * 72 + 32 + quad * 8];
                    o[dt] = __builtin_amdgcn_mfma_f32_16x16x32_bf16(vb0, pa0, o[dt], 0, 0, 0);
                    o[dt] = __builtin_amdgcn_mfma_f32_16x16x32_bf16(vb1, pa1, o[dt], 0, 0, 0);
                }
            }
        }

        // ---- in-block merge of parity partials (scratch = Ks0..Ks1 region)
        __syncthreads();                 // all PV LDS reads done
        if (wave >= 4) {
            float* p = scr + (((wave - 4) * 64 + lane) * 18);
#pragma unroll
            for (int dt = 0; dt < 4; ++dt)
#pragma unroll
                for (int r = 0; r < 4; ++r) p[dt * 4 + r] = o[dt][r];
            p[16] = m;
            p[17] = l;
        }
        __syncthreads();
        if (wave < 4) {
            const float* p = scr + ((wave * 64 + lane) * 18);
            const float m1 = p[16], l1 = p[17];
            const float M  = fmaxf(m, m1);
            const float a0 = __builtin_amdgcn_exp2f(m - M);
            const float a1 = __builtin_amdgcn_exp2f(m1 - M);
            const float invL = 1.0f / (l * a0 + l1 * a1);
#pragma unroll
            for (int dt = 0; dt < 4; ++dt) {
                float v0 = (o[dt][0] * a0 + p[dt * 4 + 0] * a1) * invL;
                float v1 = (o[dt][1] * a0 + p[dt * 4 + 1] * a1) * invL;
                float v2 = (o[dt][2] * a0 + p[dt * 4 + 2] * a1) * invL;
                float v3 = (o[dt][3] * a0 + p[dt * 4 + 3] * a1) * invL;
                uint2 uu;
                uu.x = pack_bf16x2(v0, v1);
                uu.y = pack_bf16x2(v2, v3);
                *(uint2*)&Ab[(size_t)(qr + l15) * (NH * DV) + (size_t)h * DV + dt * 16 + quad * 4] = uu;
            }
        }
        // next sel's loop-top barrier orders scratch reads vs. re-staging
    }
}

// ---------------------------------------------------------------------------
extern "C" void kernel_launch(void* const* d_in, const int* in_sizes, int n_in,
                              void* d_out, int out_size, void* d_ws, size_t ws_size,
                              hipStream_t stream) {
    const float* queries = (const float*)d_in[0];
    const float* keys    = (const float*)d_in[1];
    const float* values  = (const float*)d_in[2];
    const float* Wq      = (const float*)d_in[3];
    const float* bq      = (const float*)d_in[4];
    const float* Wk      = (const float*)d_in[5];
    const float* bk      = (const float*)d_in[6];
    const float* Wv      = (const float*)d_in[7];
    const float* bv      = (const float*)d_in[8];
    const float* Wo      = (const float*)d_in[9];
    const float* bo      = (const float*)d_in[10];
    float* out = (float*)d_out;

    const size_t MB = 1024 * 1024;
    unsigned char* w = (unsigned char*)d_ws;
    ushort* Xq  = (ushort*)(w + 0 * MB);    // [2048][2048] bf16
    ushort* Xk  = (ushort*)(w + 8 * MB);
    ushort* Xv  = (ushort*)(w + 16 * MB);
    ushort* Wqt = (ushort*)(w + 24 * MB);   // [2048][2048]
    ushort* Wkt = (ushort*)(w + 32 * MB);   // [512][2048]
    ushort* Wvt = (ushort*)(w + 34 * MB);
    ushort* Wot = (ushort*)(w + 36 * MB);   // [2048][2048]
    ushort* Qb  = (ushort*)(w + 44 * MB);   // [2048][2048]
    ushort* Kb  = (ushort*)(w + 52 * MB);   // [2048][512]
    ushort* Vtp = (ushort*)(w + 54 * MB);   // V^T [512][2048] (written directly)
    ushort* Ab  = (ushort*)(w + 56 * MB);   // [2048][2048]

    const int n8 = (S_LEN * DMODEL) / 8;
    cast3_f32_to_bf16<<<dim3(1024, 1, 3), 256, 0, stream>>>(
        queries, keys, values, Xq, Xk, Xv, n8);

    dim3 tb(32, 8);
    transpose_cast4<<<dim3(160, 64), tb, 0, stream>>>(
        Wq, Wk, Wv, Wo, Wqt, Wkt, Wvt, Wot);

    // Q projection (XCD-swizzled); softmax scale * log2(e) folded into Q
    const float QSCALE = 0.125f * 1.44269504f;
    gemm_q<<<512, 256, 0, stream>>>(Xq, Wqt, bq, Qb, DMODEL, QSCALE);

    // K and V projections fused (z=0: K, z=1: V -> V^T direct)
    gemm_kv<<<dim3(8, 16, 2), 256, 0, stream>>>(
        Xk, Xv, Wkt, Wvt, bk, bv, Kb, Vtp, DMODEL);

    // attention: 512 uniform-length blocks (parity split-K, in-block merge)
    gqa_attn_mfma<<<dim3(32, 16), 512, 0, stream>>>(Qb, Kb, Vtp, Ab);

    // O projection (XCD-swizzled): [2048,2048] @ [2048,2048] -> f32 out
    gemm_o<<<512, 256, 0, stream>>>(Ab, Wot, bo, out, DMODEL);
}